// Round 1
// baseline (1796.119 us; speedup 1.0000x reference)
//
#include <hip/hip_runtime.h>
#include <math.h>

// ---- problem constants ----
#define NNODE 6144
#define SEG   512
#define NCH   14
#define XD    42          // NCH*3
#define ED    64          // embed dim
#define HD    128
#define NCLS  25
#define KN    9
#define NPB   7           // nodes per edge-block
#define ROWS  64          // NPB*KN = 63, padded to 64
#define EDGE_BLOCKS ((NNODE + NPB - 1) / NPB)

__device__ __forceinline__ float silu_f(float x) {
  return x / (1.0f + __expf(-x));
}

// ---------------------------------------------------------------------------
// copy kernel (X init into workspace)
// ---------------------------------------------------------------------------
__global__ void copy_kernel(const float* __restrict__ src, float* __restrict__ dst, int n) {
  int i = blockIdx.x * blockDim.x + threadIdx.x;
  if (i < n) dst[i] = src[i];
}

// ---------------------------------------------------------------------------
// H init: H = (embed[S] [+ mem-MLP(Hmem)]) @ W_in + b_in      (one node/block)
// ---------------------------------------------------------------------------
__global__ __launch_bounds__(128) void h_init_kernel(
    const float* __restrict__ embed, const int* __restrict__ S,
    const float* __restrict__ W_in, const float* __restrict__ b_in,
    const float* __restrict__ Hmem,  // nullptr on round 0
    const float* __restrict__ mW1, const float* __restrict__ mb1,
    const float* __restrict__ mW2, const float* __restrict__ mb2,
    float* __restrict__ Hout)
{
  __shared__ float a1[HD];
  __shared__ float a2[HD];
  __shared__ float h0[ED];
  const int i = blockIdx.x, j = threadIdx.x;

  if (Hmem) {
    a1[j] = silu_f(Hmem[i * HD + j]);
    __syncthreads();
    float m = mb1[j];
    for (int k = 0; k < HD; ++k) m = fmaf(a1[k], mW1[k * HD + j], m);
    a2[j] = silu_f(m);
    __syncthreads();
    if (j < ED) {
      float v = mb2[j];
      for (int k = 0; k < HD; ++k) v = fmaf(a2[k], mW2[k * ED + j], v);
      h0[j] = embed[S[i] * ED + j] + v;
    }
  } else {
    if (j < ED) h0[j] = embed[S[i] * ED + j];
  }
  __syncthreads();
  float h = b_in[j];
  for (int k = 0; k < ED; ++k) h = fmaf(h0[k], W_in[k * HD + j], h);
  Hout[i * HD + j] = h;
}

// ---------------------------------------------------------------------------
// kNN: per node, 512 in-segment d2 (channel-1 coords), 9x argmin.
// d2 uses explicit _rn ops (no FMA contraction) to match the numpy reference;
// argmin tie-break prefers the lower index to match jax.lax.top_k.
// ---------------------------------------------------------------------------
__global__ __launch_bounds__(256) void knn_kernel(const float* __restrict__ X,
                                                  int* __restrict__ nbr)
{
  __shared__ float d2s[SEG];
  __shared__ float sv[256];
  __shared__ int   si[256];
  const int i = blockIdx.x;
  const int t = threadIdx.x;
  const int base = (i / SEG) * SEG;

  const float cx = X[i * XD + 3], cy = X[i * XD + 4], cz = X[i * XD + 5];
  for (int c = t; c < SEG; c += 256) {
    const int j = base + c;
    float dx = __fsub_rn(cx, X[j * XD + 3]);
    float dy = __fsub_rn(cy, X[j * XD + 4]);
    float dz = __fsub_rn(cz, X[j * XD + 5]);
    float d2 = __fadd_rn(__fadd_rn(__fmul_rn(dx, dx), __fmul_rn(dy, dy)), __fmul_rn(dz, dz));
    if (j == i) d2 = 1e9f;     // self masked (eye in `cross`)
    d2s[c] = d2;
  }
  __syncthreads();

  for (int it = 0; it < KN; ++it) {
    float bv = d2s[t];
    int   bi = t;
    {
      float v = d2s[t + 256];
      if (v < bv) { bv = v; bi = t + 256; }   // tie keeps lower index (t)
    }
    sv[t] = bv; si[t] = bi;
    __syncthreads();
    for (int s = 128; s > 0; s >>= 1) {
      if (t < s) {
        float v = sv[t + s]; int ix = si[t + s];
        if (v < sv[t] || (v == sv[t] && ix < si[t])) { sv[t] = v; si[t] = ix; }
      }
      __syncthreads();
    }
    if (t == 0) {
      nbr[i * KN + it] = base + si[0];
      d2s[si[0]] = 3e38f;     // remove from further consideration
    }
    __syncthreads();
  }
}

// ---------------------------------------------------------------------------
// 4x4 register-tile FMA helpers for the LDS-A / global-B GEMMs
// ---------------------------------------------------------------------------
__device__ __forceinline__ void tile_fma(float (&am)[4], const float4 av,
                                         const float4 b0, const float4 b1,
                                         const float4 b2, const float4 b3) {
  am[0] = fmaf(av.x, b0.x, fmaf(av.y, b1.x, fmaf(av.z, b2.x, fmaf(av.w, b3.x, am[0]))));
  am[1] = fmaf(av.x, b0.y, fmaf(av.y, b1.y, fmaf(av.z, b2.y, fmaf(av.w, b3.y, am[1]))));
  am[2] = fmaf(av.x, b0.z, fmaf(av.y, b1.z, fmaf(av.z, b2.z, fmaf(av.w, b3.z, am[2]))));
  am[3] = fmaf(av.x, b0.w, fmaf(av.y, b1.w, fmaf(av.z, b2.w, fmaf(av.w, b3.w, am[3]))));
}

__device__ __forceinline__ void gemm_k128(const float (*A)[HD], int row0,
                                          const float4* __restrict__ Wv, int wrow0,
                                          int cc, float (&acc)[4][4]) {
  for (int kk = 0; kk < HD; kk += 4) {
    const float4 b0 = Wv[(wrow0 + kk + 0) * 32 + cc];
    const float4 b1 = Wv[(wrow0 + kk + 1) * 32 + cc];
    const float4 b2 = Wv[(wrow0 + kk + 2) * 32 + cc];
    const float4 b3 = Wv[(wrow0 + kk + 3) * 32 + cc];
#pragma unroll
    for (int m = 0; m < 4; ++m) {
      const float4 av = *(const float4*)&A[row0 + m][kk];
      tile_fma(acc[m], av, b0, b1, b2, b3);
    }
  }
}

__device__ __forceinline__ void store_silu(float (*Dst)[HD], int row0, int cc,
                                           float (&acc)[4][4], const float4 bias) {
#pragma unroll
  for (int m = 0; m < 4; ++m) {
    float4 v;
    v.x = silu_f(acc[m][0] + bias.x);
    v.y = silu_f(acc[m][1] + bias.y);
    v.z = silu_f(acc[m][2] + bias.z);
    v.w = silu_f(acc[m][3] + bias.w);
    *(float4*)&Dst[row0 + m][cc * 4] = v;
  }
}

// ---------------------------------------------------------------------------
// Fused per-layer edge kernel: 7 nodes (63 edges -> 64 rows) per block.
//   ein=[Hi|Hj|radial] -> h1 -> msg -> s1 -> scale ; X += mean_k(diff*scale);
//   agg = sum_k msg ; H += MLP([H,agg]).  X,H double-buffered (Xin/Xout etc).
// LDS ~73 KB -> 2 blocks/CU (16 waves/CU).
// ---------------------------------------------------------------------------
__global__ __launch_bounds__(512, 4) void edge_layer_kernel(
    const float* __restrict__ Hin,  float* __restrict__ Hout,
    const float* __restrict__ Xin,  float* __restrict__ Xout,
    const int*   __restrict__ nbr,  const float* __restrict__ channel_w,
    const float* __restrict__ eW1, const float* __restrict__ eb1,
    const float* __restrict__ eW2, const float* __restrict__ eb2,
    const float* __restrict__ cW1, const float* __restrict__ cb1,
    const float* __restrict__ cW2, const float* __restrict__ cb2,
    const float* __restrict__ nW1, const float* __restrict__ nb1,
    const float* __restrict__ nW2, const float* __restrict__ nb2)
{
  __shared__ float HiS[NPB][HD];     // center-node H
  __shared__ float sA[ROWS][HD];     // Hj, then msg
  __shared__ float sB[ROWS][HD];     // h1, then s1, then u (node-MLP hidden)
  __shared__ float aggS[NPB][HD];
  __shared__ float XiS[NPB][XD];
  __shared__ float radialS[ROWS];
  __shared__ float scaleS[ROWS];
  __shared__ int   nbrS[ROWS];

  const int t  = threadIdx.x;
  const int n0 = blockIdx.x * NPB;
  const int nvalid = (NNODE - n0 < NPB) ? (NNODE - n0) : NPB;
  const int evalid = nvalid * KN;

  // ---- P0a: stage nbr, Xi, Hi ----
  if (t < ROWS) nbrS[t] = (t < evalid) ? nbr[n0 * KN + t] : n0;
  {
    float* XiSf = &XiS[0][0];
    for (int idx = t; idx < NPB * XD; idx += 512) {
      const int nd = idx / XD;
      XiSf[idx] = (nd < nvalid) ? Xin[n0 * XD + idx] : 0.f;
    }
    const float4* Hin4 = (const float4*)Hin;
    float4* HiS4 = (float4*)&HiS[0][0];
    for (int idx = t; idx < NPB * (HD / 4); idx += 512) {
      const int nd = idx >> 5;
      HiS4[idx] = (nd < nvalid) ? Hin4[(n0 + nd) * (HD / 4) + (idx & 31)]
                                : make_float4(0.f, 0.f, 0.f, 0.f);
    }
  }
  __syncthreads();

  // ---- P0b: stage Hj (vectorized) + radial ----
  {
    const float4* Hin4 = (const float4*)Hin;
    float4* sA4 = (float4*)&sA[0][0];
    for (int idx = t; idx < ROWS * (HD / 4); idx += 512) {
      const int row = idx >> 5;
      const int j = nbrS[row];
      sA4[idx] = (row < evalid) ? Hin4[j * (HD / 4) + (idx & 31)]
                                : make_float4(0.f, 0.f, 0.f, 0.f);
    }
  }
  if (t < ROWS) {
    float r = 0.f;
    if (t < evalid) {
      const int nd = t / KN;
      const float* xj = Xin + nbrS[t] * XD;
#pragma unroll
      for (int c = 0; c < NCH; ++c) {
        float dx = XiS[nd][c * 3 + 0] - xj[c * 3 + 0];
        float dy = XiS[nd][c * 3 + 1] - xj[c * 3 + 1];
        float dz = XiS[nd][c * 3 + 2] - xj[c * 3 + 2];
        r += channel_w[c] * (dx * dx + dy * dy + dz * dz);
      }
    }
    radialS[t] = r;
  }
  __syncthreads();

  const int rr = t >> 5;        // 0..15
  const int cc = t & 31;        // 0..31
  const int row0 = rr * 4;

  // ---- GEMM1: h1 = silu(ein @ eW1 + eb1)  (K = 257) -> sB ----
  {
    float acc[4][4] = {};
    int nd[4];
#pragma unroll
    for (int m = 0; m < 4; ++m) nd[m] = (row0 + m) / KN;
    const float4* Wv = (const float4*)eW1;
    // K part 1: Hi
    for (int kk = 0; kk < HD; kk += 4) {
      const float4 b0 = Wv[(kk + 0) * 32 + cc];
      const float4 b1 = Wv[(kk + 1) * 32 + cc];
      const float4 b2 = Wv[(kk + 2) * 32 + cc];
      const float4 b3 = Wv[(kk + 3) * 32 + cc];
#pragma unroll
      for (int m = 0; m < 4; ++m) {
        const float4 av = *(const float4*)&HiS[nd[m]][kk];
        tile_fma(acc[m], av, b0, b1, b2, b3);
      }
    }
    // K part 2: Hj
    gemm_k128((const float (*)[HD])sA, row0, Wv, HD, cc, acc);
    // K part 3: radial row (k = 256)
    {
      const float4 bl = Wv[256 * 32 + cc];
#pragma unroll
      for (int m = 0; m < 4; ++m) {
        const float a = radialS[row0 + m];
        acc[m][0] = fmaf(a, bl.x, acc[m][0]);
        acc[m][1] = fmaf(a, bl.y, acc[m][1]);
        acc[m][2] = fmaf(a, bl.z, acc[m][2]);
        acc[m][3] = fmaf(a, bl.w, acc[m][3]);
      }
    }
    store_silu(sB, row0, cc, acc, ((const float4*)eb1)[cc]);
  }
  __syncthreads();

  // ---- GEMM2: msg = silu(h1 @ eW2 + eb2) -> sA ----
  {
    float acc[4][4] = {};
    gemm_k128((const float (*)[HD])sB, row0, (const float4*)eW2, 0, cc, acc);
    store_silu(sA, row0, cc, acc, ((const float4*)eb2)[cc]);
  }
  __syncthreads();

  // ---- GEMM3: s1 = silu(msg @ cW1 + cb1) -> sB ----
  {
    float acc[4][4] = {};
    gemm_k128((const float (*)[HD])sA, row0, (const float4*)cW1, 0, cc, acc);
    store_silu(sB, row0, cc, acc, ((const float4*)cb1)[cc]);
  }
  __syncthreads();

  // ---- P4: scale = s1 . cW2 + cb2 ; agg = sum_k msg ----
  if (t < ROWS) {
    float s = cb2[0];
    for (int k = 0; k < HD; ++k) s = fmaf(sB[t][k], cW2[k], s);
    scaleS[t] = s;
  }
  {
    float* aggSf = &aggS[0][0];
    for (int idx = t; idx < NPB * HD; idx += 512) {
      const int nd = idx >> 7, col = idx & 127;
      float s = 0.f;
#pragma unroll
      for (int k = 0; k < KN; ++k) s += sA[nd * KN + k][col];
      aggSf[idx] = s;
    }
  }
  __syncthreads();

  // ---- P5: X update (diff recomputed from Xin, i.e. pre-layer X) ----
  {
    float* XiSf = &XiS[0][0];
    for (int idx = t; idx < NPB * XD; idx += 512) {
      const int nd = idx / XD, e = idx - nd * XD;
      if (nd < nvalid) {
        const float xi = XiSf[idx];
        float a = 0.f;
#pragma unroll
        for (int k = 0; k < KN; ++k) {
          const int r = nd * KN + k;
          a += (xi - Xin[nbrS[r] * XD + e]) * scaleS[r];
        }
        Xout[(n0 + nd) * XD + e] = xi + a / 9.0f;
      }
    }
  }

  // ---- P6a: u = silu([H,agg] @ nW1 + nb1) -> sB rows 0..6 ----
  {
    float* sBf = &sB[0][0];
    for (int idx = t; idx < NPB * HD; idx += 512) {
      const int nd = idx >> 7, col = idx & 127;
      float a = nb1[col];
      for (int k = 0; k < HD; ++k) a = fmaf(HiS[nd][k], nW1[k * HD + col], a);
      for (int k = 0; k < HD; ++k) a = fmaf(aggS[nd][k], nW1[(HD + k) * HD + col], a);
      sBf[idx] = silu_f(a);
    }
  }
  __syncthreads();

  // ---- P6b: Hout = H + u @ nW2 + nb2 ----
  {
    float* sBf = &sB[0][0];
    for (int idx = t; idx < NPB * HD; idx += 512) {
      const int nd = idx >> 7, col = idx & 127;
      if (nd < nvalid) {
        float a = nb2[col];
        for (int k = 0; k < HD; ++k) a = fmaf(sBf[nd * HD + k], nW2[k * HD + col], a);
        Hout[(n0 + nd) * HD + col] = HiS[nd][col] + a;
      }
    }
  }
}

// ---------------------------------------------------------------------------
// Output head: logits = silu(silu(H)@oW1+ob1)@oW2+ob2 ; also copy final X.
// ---------------------------------------------------------------------------
__global__ __launch_bounds__(128) void out_kernel(
    const float* __restrict__ H, const float* __restrict__ X,
    const float* __restrict__ oW1, const float* __restrict__ ob1,
    const float* __restrict__ oW2, const float* __restrict__ ob2,
    float* __restrict__ out)
{
  __shared__ float hs[HD];
  __shared__ float u[HD];
  const int i = blockIdx.x, j = threadIdx.x;

  hs[j] = silu_f(H[i * HD + j]);
  __syncthreads();
  float a = ob1[j];
  for (int k = 0; k < HD; ++k) a = fmaf(hs[k], oW1[k * HD + j], a);
  u[j] = silu_f(a);
  __syncthreads();
  if (j < NCLS) {
    float o = ob2[j];
    for (int k = 0; k < HD; ++k) o = fmaf(u[k], oW2[k * NCLS + j], o);
    out[i * NCLS + j] = o;
  }
  if (j < XD) out[NNODE * NCLS + i * XD + j] = X[i * XD + j];
}

// ---------------------------------------------------------------------------
extern "C" void kernel_launch(void* const* d_in, const int* in_sizes, int n_in,
                              void* d_out, int out_size, void* d_ws, size_t ws_size,
                              hipStream_t stream)
{
  const float* X0       = (const float*)d_in[0];
  const int*   S        = (const int*)  d_in[1];
  // d_in[2] = batch_id (arange // SEG) — segments are contiguous, recomputed on device
  const float* embed    = (const float*)d_in[3];
  const float* W_in     = (const float*)d_in[4];
  const float* b_in     = (const float*)d_in[5];
  const float* channelw = (const float*)d_in[6];
  const float* eW1      = (const float*)d_in[7];
  const float* eb1      = (const float*)d_in[8];
  const float* eW2      = (const float*)d_in[9];
  const float* eb2      = (const float*)d_in[10];
  const float* cW1      = (const float*)d_in[11];
  const float* cb1      = (const float*)d_in[12];
  const float* cW2      = (const float*)d_in[13];
  const float* cb2      = (const float*)d_in[14];
  const float* nW1      = (const float*)d_in[15];
  const float* nb1      = (const float*)d_in[16];
  const float* nW2      = (const float*)d_in[17];
  const float* nb2      = (const float*)d_in[18];
  const float* mW1      = (const float*)d_in[19];
  const float* mb1      = (const float*)d_in[20];
  const float* mW2      = (const float*)d_in[21];
  const float* mb2      = (const float*)d_in[22];
  const float* oW1      = (const float*)d_in[23];
  const float* ob1      = (const float*)d_in[24];
  const float* oW2      = (const float*)d_in[25];
  const float* ob2      = (const float*)d_in[26];

  char* ws = (char*)d_ws;
  const size_t HBYTES = (size_t)NNODE * HD * sizeof(float);   // 3,145,728
  const size_t XBYTES = (size_t)NNODE * XD * sizeof(float);   // 1,032,192
  float* Hb[2] = { (float*)(ws), (float*)(ws + HBYTES) };
  float* Xb[2] = { (float*)(ws + 2 * HBYTES), (float*)(ws + 2 * HBYTES + XBYTES) };
  int*   nbr   = (int*)(ws + 2 * HBYTES + 2 * XBYTES);

  copy_kernel<<<(NNODE * XD + 255) / 256, 256, 0, stream>>>(X0, Xb[0], NNODE * XD);

  int hc = 0, xc = 0;
  for (int t = 0; t < 3; ++t) {
    const float* Hmem = (t == 0) ? nullptr : Hb[hc];
    h_init_kernel<<<NNODE, HD, 0, stream>>>(embed, S, W_in, b_in, Hmem,
                                            mW1, mb1, mW2, mb2, Hb[hc ^ 1]);
    hc ^= 1;
    knn_kernel<<<NNODE, 256, 0, stream>>>(Xb[xc], nbr);
    for (int l = 0; l < 3; ++l) {
      edge_layer_kernel<<<EDGE_BLOCKS, 512, 0, stream>>>(
          Hb[hc], Hb[hc ^ 1], Xb[xc], Xb[xc ^ 1], nbr, channelw,
          eW1 + (size_t)l * 257 * HD, eb1 + (size_t)l * HD,
          eW2 + (size_t)l * HD * HD,  eb2 + (size_t)l * HD,
          cW1 + (size_t)l * HD * HD,  cb1 + (size_t)l * HD,
          cW2 + (size_t)l * HD,       cb2 + (size_t)l,
          nW1 + (size_t)l * 2 * HD * HD, nb1 + (size_t)l * HD,
          nW2 + (size_t)l * HD * HD,  nb2 + (size_t)l * HD);
      hc ^= 1; xc ^= 1;
    }
  }
  out_kernel<<<NNODE, HD, 0, stream>>>(Hb[hc], Xb[xc], oW1, ob1, oW2, ob2, (float*)d_out);
}

// Round 2
// 765.552 us; speedup vs baseline: 2.3462x; 2.3462x over previous
//
#include <hip/hip_runtime.h>
#include <math.h>

// ---- problem constants ----
#define NNODE 6144
#define SEG   512
#define NCH   14
#define XD    42          // NCH*3
#define ED    64          // embed dim
#define HD    128
#define NCLS  25
#define KN    9
#define NPB   7           // nodes per edge-block
#define ROWS  64          // NPB*KN = 63, padded to 64
#define EDGE_BLOCKS ((NNODE + NPB - 1) / NPB)

typedef __attribute__((ext_vector_type(8))) short short8;
typedef __attribute__((ext_vector_type(4))) short short4v;
typedef __attribute__((ext_vector_type(4))) float f32x4;

__device__ __forceinline__ float silu_f(float x) {
  return x / (1.0f + __expf(-x));
}
// bf16 round-nearest-even convert (finite inputs only)
__device__ __forceinline__ short f2bf(float x) {
  unsigned u = __builtin_bit_cast(unsigned, x);
  unsigned r = (u + 0x7fffu + ((u >> 16) & 1u)) >> 16;
  return (short)r;
}
__device__ __forceinline__ float bf2f(short s) {
  unsigned u = ((unsigned)(unsigned short)s) << 16;
  return __builtin_bit_cast(float, u);
}
__device__ __forceinline__ f32x4 mfma16(short8 a, short8 b, f32x4 c) {
  return __builtin_amdgcn_mfma_f32_16x16x32_bf16(a, b, c, 0, 0, 0);
}
// XOR swizzle: rows of 128 (or 256) bf16 elems; flip byte bits 4..6 by row&7
__device__ __forceinline__ int swz128(int row, int col) {
  return row * 128 + (col ^ ((row & 7) << 3));
}
__device__ __forceinline__ int swz256(int row, int col) {
  return row * 256 + (col ^ ((row & 7) << 3));
}

// ---------------------------------------------------------------------------
// weight prep: bf16 [N][K] transposed copies of the 5 GEMM weights, per layer
// ---------------------------------------------------------------------------
__global__ __launch_bounds__(256) void prep_weights(
    const float* __restrict__ eW1, const float* __restrict__ eW2,
    const float* __restrict__ cW1, const float* __restrict__ nW1,
    const float* __restrict__ nW2, short* __restrict__ out)
{
  const int mat = blockIdx.y % 5, l = blockIdx.y / 5;
  const int idx = blockIdx.x * 256 + threadIdx.x;
  const int K = (mat == 0 || mat == 3) ? 256 : 128;
  if (idx >= K * 128) return;
  const int n = idx / K, k = idx - n * K;
  const float* src;
  switch (mat) {
    case 0: src = eW1 + (size_t)l * 257 * 128; break;   // rows 0..255 (radial row handled fp32)
    case 1: src = eW2 + (size_t)l * 128 * 128; break;
    case 2: src = cW1 + (size_t)l * 128 * 128; break;
    case 3: src = nW1 + (size_t)l * 256 * 128; break;
    default: src = nW2 + (size_t)l * 128 * 128; break;
  }
  const int dofs[5] = {0, 32768, 49152, 65536, 98304};
  out[(size_t)l * 114688 + dofs[mat] + idx] = f2bf(src[k * 128 + n]);
}

// ---------------------------------------------------------------------------
__global__ void copy_kernel(const float* __restrict__ src, float* __restrict__ dst, int n) {
  int i = blockIdx.x * blockDim.x + threadIdx.x;
  if (i < n) dst[i] = src[i];
}

// ---------------------------------------------------------------------------
// H init: H = (embed[S] [+ mem-MLP(Hmem)]) @ W_in + b_in      (one node/block)
// ---------------------------------------------------------------------------
__global__ __launch_bounds__(128) void h_init_kernel(
    const float* __restrict__ embed, const int* __restrict__ S,
    const float* __restrict__ W_in, const float* __restrict__ b_in,
    const float* __restrict__ Hmem,
    const float* __restrict__ mW1, const float* __restrict__ mb1,
    const float* __restrict__ mW2, const float* __restrict__ mb2,
    float* __restrict__ Hout)
{
  __shared__ float a1[HD];
  __shared__ float a2[HD];
  __shared__ float h0[ED];
  const int i = blockIdx.x, j = threadIdx.x;

  if (Hmem) {
    a1[j] = silu_f(Hmem[i * HD + j]);
    __syncthreads();
    float m = mb1[j];
    for (int k = 0; k < HD; ++k) m = fmaf(a1[k], mW1[k * HD + j], m);
    a2[j] = silu_f(m);
    __syncthreads();
    if (j < ED) {
      float v = mb2[j];
      for (int k = 0; k < HD; ++k) v = fmaf(a2[k], mW2[k * ED + j], v);
      h0[j] = embed[S[i] * ED + j] + v;
    }
  } else {
    if (j < ED) h0[j] = embed[S[i] * ED + j];
  }
  __syncthreads();
  float h = b_in[j];
  for (int k = 0; k < ED; ++k) h = fmaf(h0[k], W_in[k * HD + j], h);
  Hout[i * HD + j] = h;
}

// ---------------------------------------------------------------------------
// kNN (unchanged; d2 bit-matches the numpy reference on round 1)
// ---------------------------------------------------------------------------
__global__ __launch_bounds__(256) void knn_kernel(const float* __restrict__ X,
                                                  int* __restrict__ nbr)
{
  __shared__ float d2s[SEG];
  __shared__ float sv[256];
  __shared__ int   si[256];
  const int i = blockIdx.x;
  const int t = threadIdx.x;
  const int base = (i / SEG) * SEG;

  const float cx = X[i * XD + 3], cy = X[i * XD + 4], cz = X[i * XD + 5];
  for (int c = t; c < SEG; c += 256) {
    const int j = base + c;
    float dx = __fsub_rn(cx, X[j * XD + 3]);
    float dy = __fsub_rn(cy, X[j * XD + 4]);
    float dz = __fsub_rn(cz, X[j * XD + 5]);
    float d2 = __fadd_rn(__fadd_rn(__fmul_rn(dx, dx), __fmul_rn(dy, dy)), __fmul_rn(dz, dz));
    if (j == i) d2 = 1e9f;
    d2s[c] = d2;
  }
  __syncthreads();

  for (int it = 0; it < KN; ++it) {
    float bv = d2s[t];
    int   bi = t;
    {
      float v = d2s[t + 256];
      if (v < bv) { bv = v; bi = t + 256; }
    }
    sv[t] = bv; si[t] = bi;
    __syncthreads();
    for (int s = 128; s > 0; s >>= 1) {
      if (t < s) {
        float v = sv[t + s]; int ix = si[t + s];
        if (v < sv[t] || (v == sv[t] && ix < si[t])) { sv[t] = v; si[t] = ix; }
      }
      __syncthreads();
    }
    if (t == 0) {
      nbr[i * KN + it] = base + si[0];
      d2s[si[0]] = 3e38f;
    }
    __syncthreads();
  }
}

// ---------------------------------------------------------------------------
// Fused per-layer edge kernel, bf16 MFMA version.
// 7 nodes (63 edges -> 64 rows) per block, 512 threads = 8 waves.
// Wave w: m-tiles {2*(w>>2), +1} x n-tiles {2*(w&3), +1} (16x16 MFMA tiles).
// ---------------------------------------------------------------------------
__global__ __launch_bounds__(512) void edge_layer_kernel(
    const float* __restrict__ Hin,  float* __restrict__ Hout,
    const float* __restrict__ Xin,  float* __restrict__ Xout,
    const int*   __restrict__ nbr,  const float* __restrict__ channel_w,
    const float* __restrict__ eW1,  const float* __restrict__ eb1,
    const float* __restrict__ eb2,  const float* __restrict__ cb1,
    const float* __restrict__ cW2,  const float* __restrict__ cb2,
    const float* __restrict__ nb1,  const float* __restrict__ nb2,
    const short* __restrict__ W1T,  const short* __restrict__ W2T,
    const short* __restrict__ C1T,  const short* __restrict__ N1T,
    const short* __restrict__ N2T)
{
  __shared__ short HjB[ROWS * HD];      // swizzled bf16: Hj, then msg
  __shared__ short sB [ROWS * HD];      // swizzled bf16: h1, then s1
  __shared__ short HiB[8 * HD];         // linear bf16 Hi (row-broadcast reads)
  __shared__ float HiS[NPB][HD];        // fp32 Hi for final H update
  __shared__ short nodeA[16 * 256];     // swizzled bf16 [Hi | agg], rows 7..15 zero
  __shared__ short uT[16 * HD];         // swizzled bf16 node hidden
  __shared__ float XiS[NPB][XD];
  __shared__ float radialS[ROWS];
  __shared__ float scaleS[ROWS];
  __shared__ int   nbrS[ROWS];

  const int t  = threadIdx.x;
  const int n0 = blockIdx.x * NPB;
  const int nvalid = (NNODE - n0 < NPB) ? (NNODE - n0) : NPB;
  const int evalid = nvalid * KN;

  // ---- P0a: nbr, Xi, Hi(fp32+bf16) ----
  if (t < ROWS) nbrS[t] = (t < evalid) ? nbr[n0 * KN + t] : n0;
  {
    float* XiSf = &XiS[0][0];
    for (int idx = t; idx < NPB * XD; idx += 512) {
      const int nd = idx / XD;
      XiSf[idx] = (nd < nvalid) ? Xin[n0 * XD + idx] : 0.f;
    }
    for (int idx = t; idx < 8 * HD; idx += 512) {
      const int r = idx >> 7, c = idx & 127;
      const float v = (r < nvalid) ? Hin[(n0 + r) * HD + c] : 0.f;
      if (r < NPB) HiS[r][c] = v;
      HiB[idx] = f2bf(v);
    }
  }
  __syncthreads();

  // ---- P0b: Hj (bf16, swizzled) + radial ----
  {
    const float4* Hin4 = (const float4*)Hin;
    for (int idx = t; idx < ROWS * (HD / 4); idx += 512) {
      const int row = idx >> 5, c4 = idx & 31;
      float4 v = make_float4(0.f, 0.f, 0.f, 0.f);
      if (row < evalid) v = Hin4[nbrS[row] * 32 + c4];
      short4v s;
      s.x = f2bf(v.x); s.y = f2bf(v.y); s.z = f2bf(v.z); s.w = f2bf(v.w);
      *(short4v*)&HjB[swz128(row, c4 * 4)] = s;
    }
  }
  if (t < ROWS) {
    float r = 0.f;
    if (t < evalid) {
      const int nd = t / KN;
      const float* xj = Xin + nbrS[t] * XD;
#pragma unroll
      for (int c = 0; c < NCH; ++c) {
        float dx = XiS[nd][c * 3 + 0] - xj[c * 3 + 0];
        float dy = XiS[nd][c * 3 + 1] - xj[c * 3 + 1];
        float dz = XiS[nd][c * 3 + 2] - xj[c * 3 + 2];
        r += channel_w[c] * (dx * dx + dy * dy + dz * dz);
      }
    }
    radialS[t] = r;
  }
  __syncthreads();

  const int wid  = t >> 6;       // 0..7
  const int lane = t & 63;
  const int m2 = wid >> 2;       // 0..1
  const int n2 = wid & 3;        // 0..3
  const int lr = lane & 15;      // row/col within 16x16 tile
  const int lk = lane >> 4;      // k-group 0..3
  const int rA0 = (m2 * 2) * 16 + lr;       // A row, m-tile 0
  const int rA1 = rA0 + 16;                 // A row, m-tile 1
  const int nd0 = rA0 / 9, nd1 = rA1 / 9;   // center-node row for Hi part

  // ---- GEMM1: h1 = silu([Hi|Hj|radial] @ eW1 + eb1) -> sB ----
  {
    f32x4 acc[2][2] = {};
    const short* b0p = W1T + ((n2 * 2) * 16 + lr) * 256;
    const short* b1p = b0p + 16 * 256;
#pragma unroll
    for (int ks = 0; ks < 8; ++ks) {
      const int k0 = ks * 32 + lk * 8;
      short8 a0, a1;
      if (ks < 4) {
        a0 = *(const short8*)&HiB[nd0 * HD + k0];
        a1 = *(const short8*)&HiB[nd1 * HD + k0];
      } else {
        a0 = *(const short8*)&HjB[swz128(rA0, k0 - 128)];
        a1 = *(const short8*)&HjB[swz128(rA1, k0 - 128)];
      }
      const short8 b0 = *(const short8*)(b0p + k0);
      const short8 b1 = *(const short8*)(b1p + k0);
      acc[0][0] = mfma16(a0, b0, acc[0][0]);
      acc[0][1] = mfma16(a0, b1, acc[0][1]);
      acc[1][0] = mfma16(a1, b0, acc[1][0]);
      acc[1][1] = mfma16(a1, b1, acc[1][1]);
    }
#pragma unroll
    for (int ni = 0; ni < 2; ++ni) {
      const int col = (n2 * 2 + ni) * 16 + lr;
      const float bias = eb1[col];
      const float w256 = eW1[256 * HD + col];
#pragma unroll
      for (int mi = 0; mi < 2; ++mi) {
        const int rb = (m2 * 2 + mi) * 16 + lk * 4;
#pragma unroll
        for (int g = 0; g < 4; ++g) {
          const int row = rb + g;
          const float v = acc[mi][ni][g] + radialS[row] * w256 + bias;
          sB[swz128(row, col)] = f2bf(silu_f(v));
        }
      }
    }
  }
  __syncthreads();

  // ---- GEMM2: msg = silu(h1 @ eW2 + eb2) -> HjB ----
  {
    f32x4 acc[2][2] = {};
    const short* b0p = W2T + ((n2 * 2) * 16 + lr) * 128;
    const short* b1p = b0p + 16 * 128;
#pragma unroll
    for (int ks = 0; ks < 4; ++ks) {
      const int k0 = ks * 32 + lk * 8;
      const short8 a0 = *(const short8*)&sB[swz128(rA0, k0)];
      const short8 a1 = *(const short8*)&sB[swz128(rA1, k0)];
      const short8 b0 = *(const short8*)(b0p + k0);
      const short8 b1 = *(const short8*)(b1p + k0);
      acc[0][0] = mfma16(a0, b0, acc[0][0]);
      acc[0][1] = mfma16(a0, b1, acc[0][1]);
      acc[1][0] = mfma16(a1, b0, acc[1][0]);
      acc[1][1] = mfma16(a1, b1, acc[1][1]);
    }
#pragma unroll
    for (int ni = 0; ni < 2; ++ni) {
      const int col = (n2 * 2 + ni) * 16 + lr;
      const float bias = eb2[col];
#pragma unroll
      for (int mi = 0; mi < 2; ++mi) {
        const int rb = (m2 * 2 + mi) * 16 + lk * 4;
#pragma unroll
        for (int g = 0; g < 4; ++g)
          HjB[swz128(rb + g, col)] = f2bf(silu_f(acc[mi][ni][g] + bias));
      }
    }
  }
  __syncthreads();

  // ---- GEMM3: s1 = silu(msg @ cW1 + cb1) -> sB ----
  {
    f32x4 acc[2][2] = {};
    const short* b0p = C1T + ((n2 * 2) * 16 + lr) * 128;
    const short* b1p = b0p + 16 * 128;
#pragma unroll
    for (int ks = 0; ks < 4; ++ks) {
      const int k0 = ks * 32 + lk * 8;
      const short8 a0 = *(const short8*)&HjB[swz128(rA0, k0)];
      const short8 a1 = *(const short8*)&HjB[swz128(rA1, k0)];
      const short8 b0 = *(const short8*)(b0p + k0);
      const short8 b1 = *(const short8*)(b1p + k0);
      acc[0][0] = mfma16(a0, b0, acc[0][0]);
      acc[0][1] = mfma16(a0, b1, acc[0][1]);
      acc[1][0] = mfma16(a1, b0, acc[1][0]);
      acc[1][1] = mfma16(a1, b1, acc[1][1]);
    }
#pragma unroll
    for (int ni = 0; ni < 2; ++ni) {
      const int col = (n2 * 2 + ni) * 16 + lr;
      const float bias = cb1[col];
#pragma unroll
      for (int mi = 0; mi < 2; ++mi) {
        const int rb = (m2 * 2 + mi) * 16 + lk * 4;
#pragma unroll
        for (int g = 0; g < 4; ++g)
          sB[swz128(rb + g, col)] = f2bf(silu_f(acc[mi][ni][g] + bias));
      }
    }
  }
  __syncthreads();

  // ---- P4: scale = s1 . cW2 + cb2 ; nodeA = [Hi | sum_k msg] (bf16) ----
  if (t < ROWS) {
    float s = cb2[0];
    for (int k = 0; k < HD; ++k) s = fmaf(bf2f(sB[swz128(t, k)]), cW2[k], s);
    scaleS[t] = s;
  }
  for (int idx = t; idx < 16 * 256; idx += 512) {
    const int r = idx >> 8, c = idx & 255;
    float v = 0.f;
    if (r < nvalid) {
      if (c < HD) v = HiS[r][c];
      else {
        const int col = c - HD;
#pragma unroll
        for (int k = 0; k < KN; ++k) v += bf2f(HjB[swz128(r * KN + k, col)]);
      }
    }
    nodeA[swz256(r, c)] = f2bf(v);
  }
  __syncthreads();

  // ---- P5: X update (fp32, diff from Xin) ----
  {
    float* XiSf = &XiS[0][0];
    for (int idx = t; idx < NPB * XD; idx += 512) {
      const int nd = idx / XD, e = idx - nd * XD;
      if (nd < nvalid) {
        const float xi = XiSf[idx];
        float a = 0.f;
#pragma unroll
        for (int k = 0; k < KN; ++k) {
          const int r = nd * KN + k;
          a += (xi - Xin[nbrS[r] * XD + e]) * scaleS[r];
        }
        Xout[(n0 + nd) * XD + e] = xi + a / 9.0f;
      }
    }
  }

  // ---- NG1: u = silu([H|agg] @ nW1 + nb1) -> uT  (wave w = n-tile w) ----
  {
    f32x4 acc = {};
    const short* bp = N1T + (wid * 16 + lr) * 256;
#pragma unroll
    for (int ks = 0; ks < 8; ++ks) {
      const int k0 = ks * 32 + lk * 8;
      const short8 a = *(const short8*)&nodeA[swz256(lr, k0)];
      const short8 b = *(const short8*)(bp + k0);
      acc = mfma16(a, b, acc);
    }
    const int col = wid * 16 + lr;
    const float bias = nb1[col];
#pragma unroll
    for (int g = 0; g < 4; ++g)
      uT[swz128(lk * 4 + g, col)] = f2bf(silu_f(acc[g] + bias));
  }
  __syncthreads();

  // ---- NG2: Hout = Hi + u @ nW2 + nb2 ----
  {
    f32x4 acc = {};
    const short* bp = N2T + (wid * 16 + lr) * 128;
#pragma unroll
    for (int ks = 0; ks < 4; ++ks) {
      const int k0 = ks * 32 + lk * 8;
      const short8 a = *(const short8*)&uT[swz128(lr, k0)];
      const short8 b = *(const short8*)(bp + k0);
      acc = mfma16(a, b, acc);
    }
    const int col = wid * 16 + lr;
    const float bias = nb2[col];
#pragma unroll
    for (int g = 0; g < 4; ++g) {
      const int row = lk * 4 + g;
      if (row < nvalid)
        Hout[(n0 + row) * HD + col] = HiS[row][col] + acc[g] + bias;
    }
  }
}

// ---------------------------------------------------------------------------
// Output head (fp32, unchanged)
// ---------------------------------------------------------------------------
__global__ __launch_bounds__(128) void out_kernel(
    const float* __restrict__ H, const float* __restrict__ X,
    const float* __restrict__ oW1, const float* __restrict__ ob1,
    const float* __restrict__ oW2, const float* __restrict__ ob2,
    float* __restrict__ out)
{
  __shared__ float hs[HD];
  __shared__ float u[HD];
  const int i = blockIdx.x, j = threadIdx.x;

  hs[j] = silu_f(H[i * HD + j]);
  __syncthreads();
  float a = ob1[j];
  for (int k = 0; k < HD; ++k) a = fmaf(hs[k], oW1[k * HD + j], a);
  u[j] = silu_f(a);
  __syncthreads();
  if (j < NCLS) {
    float o = ob2[j];
    for (int k = 0; k < HD; ++k) o = fmaf(u[k], oW2[k * NCLS + j], o);
    out[i * NCLS + j] = o;
  }
  if (j < XD) out[NNODE * NCLS + i * XD + j] = X[i * XD + j];
}

// ---------------------------------------------------------------------------
extern "C" void kernel_launch(void* const* d_in, const int* in_sizes, int n_in,
                              void* d_out, int out_size, void* d_ws, size_t ws_size,
                              hipStream_t stream)
{
  const float* X0       = (const float*)d_in[0];
  const int*   S        = (const int*)  d_in[1];
  const float* embed    = (const float*)d_in[3];
  const float* W_in     = (const float*)d_in[4];
  const float* b_in     = (const float*)d_in[5];
  const float* channelw = (const float*)d_in[6];
  const float* eW1      = (const float*)d_in[7];
  const float* eb1      = (const float*)d_in[8];
  const float* eW2      = (const float*)d_in[9];
  const float* eb2      = (const float*)d_in[10];
  const float* cW1      = (const float*)d_in[11];
  const float* cb1      = (const float*)d_in[12];
  const float* cW2      = (const float*)d_in[13];
  const float* cb2      = (const float*)d_in[14];
  const float* nW1      = (const float*)d_in[15];
  const float* nb1      = (const float*)d_in[16];
  const float* nW2      = (const float*)d_in[17];
  const float* nb2      = (const float*)d_in[18];
  const float* mW1      = (const float*)d_in[19];
  const float* mb1      = (const float*)d_in[20];
  const float* mW2      = (const float*)d_in[21];
  const float* mb2      = (const float*)d_in[22];
  const float* oW1      = (const float*)d_in[23];
  const float* ob1      = (const float*)d_in[24];
  const float* oW2      = (const float*)d_in[25];
  const float* ob2      = (const float*)d_in[26];

  char* ws = (char*)d_ws;
  const size_t HBYTES = (size_t)NNODE * HD * sizeof(float);   // 3,145,728
  const size_t XBYTES = (size_t)NNODE * XD * sizeof(float);   // 1,032,192
  float* Hb[2] = { (float*)(ws), (float*)(ws + HBYTES) };
  float* Xb[2] = { (float*)(ws + 2 * HBYTES), (float*)(ws + 2 * HBYTES + XBYTES) };
  int*   nbr   = (int*)(ws + 2 * HBYTES + 2 * XBYTES);
  short* Wbf   = (short*)(ws + 2 * HBYTES + 2 * XBYTES + (size_t)NNODE * KN * sizeof(int));

  prep_weights<<<dim3(128, 15), 256, 0, stream>>>(eW1, eW2, cW1, nW1, nW2, Wbf);
  copy_kernel<<<(NNODE * XD + 255) / 256, 256, 0, stream>>>(X0, Xb[0], NNODE * XD);

  int hc = 0, xc = 0;
  for (int t = 0; t < 3; ++t) {
    const float* Hmem = (t == 0) ? nullptr : Hb[hc];
    h_init_kernel<<<NNODE, HD, 0, stream>>>(embed, S, W_in, b_in, Hmem,
                                            mW1, mb1, mW2, mb2, Hb[hc ^ 1]);
    hc ^= 1;
    knn_kernel<<<NNODE, 256, 0, stream>>>(Xb[xc], nbr);
    for (int l = 0; l < 3; ++l) {
      const short* Wl = Wbf + (size_t)l * 114688;
      edge_layer_kernel<<<EDGE_BLOCKS, 512, 0, stream>>>(
          Hb[hc], Hb[hc ^ 1], Xb[xc], Xb[xc ^ 1], nbr, channelw,
          eW1 + (size_t)l * 257 * HD, eb1 + (size_t)l * HD,
          eb2 + (size_t)l * HD,  cb1 + (size_t)l * HD,
          cW2 + (size_t)l * HD,  cb2 + (size_t)l,
          nb1 + (size_t)l * HD,  nb2 + (size_t)l * HD,
          Wl, Wl + 32768, Wl + 49152, Wl + 65536, Wl + 98304);
      hc ^= 1; xc ^= 1;
    }
  }
  out_kernel<<<NNODE, HD, 0, stream>>>(Hb[hc], Xb[xc], oW1, ob1, oW2, ob2, (float*)d_out);
}

// Round 3
// 666.331 us; speedup vs baseline: 2.6955x; 1.1489x over previous
//
#include <hip/hip_runtime.h>
#include <math.h>

// ---- problem constants ----
#define NNODE 6144
#define SEG   512
#define NCH   14
#define XD    42          // NCH*3
#define ED    64          // embed dim
#define HD    128
#define NCLS  25
#define KN    9
#define NPB   7           // nodes per edge-block
#define ROWS  64          // NPB*KN = 63, padded to 64
#define EDGE_BLOCKS ((NNODE + NPB - 1) / NPB)

typedef __attribute__((ext_vector_type(8))) short short8;
typedef __attribute__((ext_vector_type(4))) short short4v;
typedef __attribute__((ext_vector_type(4))) float f32x4;

__device__ __forceinline__ float silu_f(float x) {
  return x / (1.0f + __expf(-x));
}
// bf16 round-nearest-even convert (finite inputs only)
__device__ __forceinline__ short f2bf(float x) {
  unsigned u = __builtin_bit_cast(unsigned, x);
  unsigned r = (u + 0x7fffu + ((u >> 16) & 1u)) >> 16;
  return (short)r;
}
__device__ __forceinline__ float bf2f(short s) {
  unsigned u = ((unsigned)(unsigned short)s) << 16;
  return __builtin_bit_cast(float, u);
}
__device__ __forceinline__ f32x4 mfma16(short8 a, short8 b, f32x4 c) {
  return __builtin_amdgcn_mfma_f32_16x16x32_bf16(a, b, c, 0, 0, 0);
}
// XOR swizzle: rows of 128 (or 256) bf16 elems; flip byte bits 4..6 by row&7
__device__ __forceinline__ int swz128(int row, int col) {
  return row * 128 + (col ^ ((row & 7) << 3));
}
__device__ __forceinline__ int swz256(int row, int col) {
  return row * 256 + (col ^ ((row & 7) << 3));
}

// ---------------------------------------------------------------------------
// weight prep: bf16 [N][K] transposed copies of the 5 GEMM weights, per layer
// ---------------------------------------------------------------------------
__global__ __launch_bounds__(256) void prep_weights(
    const float* __restrict__ eW1, const float* __restrict__ eW2,
    const float* __restrict__ cW1, const float* __restrict__ nW1,
    const float* __restrict__ nW2, short* __restrict__ out)
{
  const int mat = blockIdx.y % 5, l = blockIdx.y / 5;
  const int idx = blockIdx.x * 256 + threadIdx.x;
  const int K = (mat == 0 || mat == 3) ? 256 : 128;
  if (idx >= K * 128) return;
  const int n = idx / K, k = idx - n * K;
  const float* src;
  switch (mat) {
    case 0: src = eW1 + (size_t)l * 257 * 128; break;   // rows 0..255 (radial row fp32)
    case 1: src = eW2 + (size_t)l * 128 * 128; break;
    case 2: src = cW1 + (size_t)l * 128 * 128; break;
    case 3: src = nW1 + (size_t)l * 256 * 128; break;
    default: src = nW2 + (size_t)l * 128 * 128; break;
  }
  const int dofs[5] = {0, 32768, 49152, 65536, 98304};
  out[(size_t)l * 114688 + dofs[mat] + idx] = f2bf(src[k * 128 + n]);
}

// ---------------------------------------------------------------------------
__global__ void copy_kernel(const float* __restrict__ src, float* __restrict__ dst, int n) {
  int i = blockIdx.x * blockDim.x + threadIdx.x;
  if (i < n) dst[i] = src[i];
}

// ---------------------------------------------------------------------------
// pq_kernel: PQ[i][c] = sum_k H[i][k] * (c<128 ? eW1[k][c] : eW1[128+k][c-128])
// 32 rows per block, 512 threads (8 waves), fp32 output.
// ---------------------------------------------------------------------------
__global__ __launch_bounds__(512) void pq_kernel(
    const float* __restrict__ Hin, const short* __restrict__ W1T,
    float* __restrict__ PQ)
{
  __shared__ __align__(16) short A[32 * HD];
  const int t = threadIdx.x;
  const int m0 = blockIdx.x * 32;

  const float4* H4 = (const float4*)(Hin + (size_t)m0 * HD);
  for (int idx = t; idx < 32 * 32; idx += 512) {
    const int r = idx >> 5, c4 = idx & 31;
    float4 v = H4[r * 32 + c4];
    short4v s;
    s.x = f2bf(v.x); s.y = f2bf(v.y); s.z = f2bf(v.z); s.w = f2bf(v.w);
    *(short4v*)&A[swz128(r, c4 * 4)] = s;
  }
  __syncthreads();

  const int wid = t >> 6, lane = t & 63;
  const int lr = lane & 15, lk = lane >> 4;
  const int mt = wid >> 2;            // m-tile 0..1
  const int nb = (wid & 3) * 4;       // first of 4 n-tiles
  const int rA = mt * 16 + lr;

  f32x4 acc[4] = {};
#pragma unroll
  for (int ks = 0; ks < 4; ++ks) {
    const int k0 = ks * 32 + lk * 8;
    const short8 a = *(const short8*)&A[swz128(rA, k0)];
#pragma unroll
    for (int ni = 0; ni < 4; ++ni) {
      const int c = (nb + ni) * 16 + lr;
      const short* bp = (c < HD) ? (W1T + c * 256 + k0)
                                 : (W1T + (c - HD) * 256 + HD + k0);
      const short8 b = *(const short8*)bp;
      acc[ni] = mfma16(a, b, acc[ni]);
    }
  }
#pragma unroll
  for (int ni = 0; ni < 4; ++ni) {
    const int c = (nb + ni) * 16 + lr;
#pragma unroll
    for (int g = 0; g < 4; ++g) {
      const int row = mt * 16 + lk * 4 + g;
      PQ[(size_t)(m0 + row) * 256 + c] = acc[ni][g];
    }
  }
}

// ---------------------------------------------------------------------------
// H init: H = (embed[S] [+ mem-MLP(Hmem)]) @ W_in + b_in  (4-way ILP unroll)
// ---------------------------------------------------------------------------
__global__ __launch_bounds__(128) void h_init_kernel(
    const float* __restrict__ embed, const int* __restrict__ S,
    const float* __restrict__ W_in, const float* __restrict__ b_in,
    const float* __restrict__ Hmem,
    const float* __restrict__ mW1, const float* __restrict__ mb1,
    const float* __restrict__ mW2, const float* __restrict__ mb2,
    float* __restrict__ Hout)
{
  __shared__ float a1[HD];
  __shared__ float a2[HD];
  __shared__ float h0[ED];
  const int i = blockIdx.x, j = threadIdx.x;

  if (Hmem) {
    a1[j] = silu_f(Hmem[i * HD + j]);
    __syncthreads();
    float m0 = 0.f, m1 = 0.f, m2 = 0.f, m3 = 0.f;
    for (int k = 0; k < HD; k += 4) {
      m0 = fmaf(a1[k + 0], mW1[(k + 0) * HD + j], m0);
      m1 = fmaf(a1[k + 1], mW1[(k + 1) * HD + j], m1);
      m2 = fmaf(a1[k + 2], mW1[(k + 2) * HD + j], m2);
      m3 = fmaf(a1[k + 3], mW1[(k + 3) * HD + j], m3);
    }
    a2[j] = silu_f(mb1[j] + ((m0 + m1) + (m2 + m3)));
    __syncthreads();
    if (j < ED) {
      float v0 = 0.f, v1 = 0.f, v2 = 0.f, v3 = 0.f;
      for (int k = 0; k < HD; k += 4) {
        v0 = fmaf(a2[k + 0], mW2[(k + 0) * ED + j], v0);
        v1 = fmaf(a2[k + 1], mW2[(k + 1) * ED + j], v1);
        v2 = fmaf(a2[k + 2], mW2[(k + 2) * ED + j], v2);
        v3 = fmaf(a2[k + 3], mW2[(k + 3) * ED + j], v3);
      }
      h0[j] = embed[S[i] * ED + j] + mb2[j] + ((v0 + v1) + (v2 + v3));
    }
  } else {
    if (j < ED) h0[j] = embed[S[i] * ED + j];
  }
  __syncthreads();
  float h0a = 0.f, h1a = 0.f, h2a = 0.f, h3a = 0.f;
  for (int k = 0; k < ED; k += 4) {
    h0a = fmaf(h0[k + 0], W_in[(k + 0) * HD + j], h0a);
    h1a = fmaf(h0[k + 1], W_in[(k + 1) * HD + j], h1a);
    h2a = fmaf(h0[k + 2], W_in[(k + 2) * HD + j], h2a);
    h3a = fmaf(h0[k + 3], W_in[(k + 3) * HD + j], h3a);
  }
  Hout[i * HD + j] = b_in[j] + ((h0a + h1a) + (h2a + h3a));
}

// ---------------------------------------------------------------------------
// kNN: one wave per node, candidates in registers, zero barriers/LDS.
// d2 uses explicit _rn ops (no FMA contraction) to match the numpy reference;
// (v, idx)-lexicographic min matches jax.lax.top_k tie-breaking.
// ---------------------------------------------------------------------------
__global__ __launch_bounds__(256) void knn_kernel(const float* __restrict__ X,
                                                  int* __restrict__ nbr)
{
  const int w = threadIdx.x >> 6, lane = threadIdx.x & 63;
  const int i = blockIdx.x * 4 + w;
  const int base = (i / SEG) * SEG;

  const float cx = X[i * XD + 3], cy = X[i * XD + 4], cz = X[i * XD + 5];
  float dv[8];
  int   di[8];
#pragma unroll
  for (int q = 0; q < 8; ++q) {
    const int j = base + lane + q * 64;
    float dx = __fsub_rn(cx, X[j * XD + 3]);
    float dy = __fsub_rn(cy, X[j * XD + 4]);
    float dz = __fsub_rn(cz, X[j * XD + 5]);
    float d2 = __fadd_rn(__fadd_rn(__fmul_rn(dx, dx), __fmul_rn(dy, dy)), __fmul_rn(dz, dz));
    if (j == i) d2 = 1e9f;
    dv[q] = d2; di[q] = j;
  }
  for (int it = 0; it < KN; ++it) {
    float bv = dv[0]; int bi = di[0];
#pragma unroll
    for (int q = 1; q < 8; ++q)
      if (dv[q] < bv || (dv[q] == bv && di[q] < bi)) { bv = dv[q]; bi = di[q]; }
#pragma unroll
    for (int m = 1; m < 64; m <<= 1) {
      float ov = __shfl_xor(bv, m, 64);
      int   oi = __shfl_xor(bi, m, 64);
      if (ov < bv || (ov == bv && oi < bi)) { bv = ov; bi = oi; }
    }
    if (lane == 0) nbr[i * KN + it] = bi;
    const int rel = bi - base;
    const int oq = rel >> 6;
#pragma unroll
    for (int q = 0; q < 8; ++q)
      if (q == oq && (rel & 63) == lane) dv[q] = 3e38f;
  }
}

// ---------------------------------------------------------------------------
// Fused per-layer edge kernel (factored GEMM1 via PQ).
// 7 nodes (63 edges -> 64 rows) per block, 512 threads = 8 waves, 7 barriers.
// ---------------------------------------------------------------------------
__global__ __launch_bounds__(512) void edge_layer_kernel(
    const float* __restrict__ Hin,  float* __restrict__ Hout,
    const float* __restrict__ Xin,  float* __restrict__ Xout,
    const int*   __restrict__ nbr,  const float* __restrict__ channel_w,
    const float* __restrict__ PQ,
    const float* __restrict__ eW1,  const float* __restrict__ eb1,
    const float* __restrict__ eb2,  const float* __restrict__ cb1,
    const float* __restrict__ cW2,  const float* __restrict__ cb2,
    const float* __restrict__ nb1,  const float* __restrict__ nb2,
    const short* __restrict__ W2T,  const short* __restrict__ C1T,
    const short* __restrict__ N1T,  const short* __restrict__ N2T)
{
  __shared__ __align__(16) short bufA[ROWS * HD];   // h1, then s1
  __shared__ __align__(16) short bufB[ROWS * HD];   // msg
  __shared__ __align__(16) short nodeA[16 * 256];   // [Hi | agg] bf16, swizzled
  __shared__ __align__(16) short uT[16 * HD];       // node hidden
  __shared__ float XiS[NPB][XD];
  __shared__ float radialS[ROWS];
  __shared__ float scaleS[ROWS];
  __shared__ int   nbrS[ROWS];

  const int t  = threadIdx.x;
  const int n0 = blockIdx.x * NPB;
  const int nvalid = (NNODE - n0 < NPB) ? (NNODE - n0) : NPB;
  const int evalid = nvalid * KN;

  // ---- P0: nbr + radial (wave 0) ; XiS staging (all) ----
  if (t < ROWS) {
    const int j = (t < evalid) ? nbr[n0 * KN + t] : n0;
    nbrS[t] = j;
    float r = 0.f;
    if (t < evalid) {
      const int nd = t / KN;
      const float* xi = Xin + (size_t)(n0 + nd) * XD;
      const float* xj = Xin + (size_t)j * XD;
#pragma unroll
      for (int c = 0; c < NCH; ++c) {
        float dx = xi[c * 3 + 0] - xj[c * 3 + 0];
        float dy = xi[c * 3 + 1] - xj[c * 3 + 1];
        float dz = xi[c * 3 + 2] - xj[c * 3 + 2];
        r += channel_w[c] * (dx * dx + dy * dy + dz * dz);
      }
    }
    radialS[t] = r;
  }
  {
    float* XiSf = &XiS[0][0];
    for (int idx = t; idx < NPB * XD; idx += 512) {
      const int nd = idx / XD;
      XiSf[idx] = (nd < nvalid) ? Xin[n0 * XD + idx] : 0.f;
    }
  }
  __syncthreads();

  // ---- P1: h1 = silu(P[i] + Q[j] + radial*w256 + eb1) -> bufA (bf16) ----
  {
    const float4* PQ4 = (const float4*)PQ;
    const float4* w2564 = (const float4*)(eW1 + 256 * HD);
    const float4* eb14 = (const float4*)eb1;
    for (int idx = t; idx < ROWS * (HD / 4); idx += 512) {
      const int row = idx >> 5, c4 = idx & 31;
      const int nd = row / KN;
      const int inode = n0 + ((nd < nvalid) ? nd : 0);
      const int jnode = nbrS[row];
      const float4 p = PQ4[(size_t)inode * 64 + c4];
      const float4 q = PQ4[(size_t)jnode * 64 + 32 + c4];
      const float rad = radialS[row];
      const float4 w = w2564[c4];
      const float4 bb = eb14[c4];
      short4v s;
      s.x = f2bf(silu_f(p.x + q.x + rad * w.x + bb.x));
      s.y = f2bf(silu_f(p.y + q.y + rad * w.y + bb.y));
      s.z = f2bf(silu_f(p.z + q.z + rad * w.z + bb.z));
      s.w = f2bf(silu_f(p.w + q.w + rad * w.w + bb.w));
      *(short4v*)&bufA[swz128(row, c4 * 4)] = s;
    }
  }
  __syncthreads();

  const int wid  = t >> 6;       // 0..7
  const int lane = t & 63;
  const int m2 = wid >> 2;       // 0..1
  const int n2 = wid & 3;        // 0..3
  const int lr = lane & 15;
  const int lk = lane >> 4;
  const int rA0 = (m2 * 2) * 16 + lr;
  const int rA1 = rA0 + 16;

  // ---- G2: msg = silu(h1 @ eW2 + eb2) -> bufB ----
  {
    f32x4 acc[2][2] = {};
    const short* b0p = W2T + ((n2 * 2) * 16 + lr) * 128;
    const short* b1p = b0p + 16 * 128;
#pragma unroll
    for (int ks = 0; ks < 4; ++ks) {
      const int k0 = ks * 32 + lk * 8;
      const short8 a0 = *(const short8*)&bufA[swz128(rA0, k0)];
      const short8 a1 = *(const short8*)&bufA[swz128(rA1, k0)];
      const short8 b0 = *(const short8*)(b0p + k0);
      const short8 b1 = *(const short8*)(b1p + k0);
      acc[0][0] = mfma16(a0, b0, acc[0][0]);
      acc[0][1] = mfma16(a0, b1, acc[0][1]);
      acc[1][0] = mfma16(a1, b0, acc[1][0]);
      acc[1][1] = mfma16(a1, b1, acc[1][1]);
    }
#pragma unroll
    for (int ni = 0; ni < 2; ++ni) {
      const int col = (n2 * 2 + ni) * 16 + lr;
      const float bias = eb2[col];
#pragma unroll
      for (int mi = 0; mi < 2; ++mi) {
        const int rb = (m2 * 2 + mi) * 16 + lk * 4;
#pragma unroll
        for (int g = 0; g < 4; ++g)
          bufB[swz128(rb + g, col)] = f2bf(silu_f(acc[mi][ni][g] + bias));
      }
    }
  }
  __syncthreads();

  // ---- G3: s1 = silu(msg @ cW1 + cb1) -> bufA ----
  {
    f32x4 acc[2][2] = {};
    const short* b0p = C1T + ((n2 * 2) * 16 + lr) * 128;
    const short* b1p = b0p + 16 * 128;
#pragma unroll
    for (int ks = 0; ks < 4; ++ks) {
      const int k0 = ks * 32 + lk * 8;
      const short8 a0 = *(const short8*)&bufB[swz128(rA0, k0)];
      const short8 a1 = *(const short8*)&bufB[swz128(rA1, k0)];
      const short8 b0 = *(const short8*)(b0p + k0);
      const short8 b1 = *(const short8*)(b1p + k0);
      acc[0][0] = mfma16(a0, b0, acc[0][0]);
      acc[0][1] = mfma16(a0, b1, acc[0][1]);
      acc[1][0] = mfma16(a1, b0, acc[1][0]);
      acc[1][1] = mfma16(a1, b1, acc[1][1]);
    }
#pragma unroll
    for (int ni = 0; ni < 2; ++ni) {
      const int col = (n2 * 2 + ni) * 16 + lr;
      const float bias = cb1[col];
#pragma unroll
      for (int mi = 0; mi < 2; ++mi) {
        const int rb = (m2 * 2 + mi) * 16 + lk * 4;
#pragma unroll
        for (int g = 0; g < 4; ++g)
          bufA[swz128(rb + g, col)] = f2bf(silu_f(acc[mi][ni][g] + bias));
      }
    }
  }
  __syncthreads();

  // ---- P4: scale (8 thr/row shuffle-reduce) ; nodeA = [Hi | agg] ----
  {
    const int row = t >> 3, part = t & 7;
    float s = 0.f;
#pragma unroll
    for (int qq = 0; qq < 16; ++qq) {
      const int k = part * 16 + qq;
      s = fmaf(bf2f(bufA[swz128(row, k)]), cW2[k], s);
    }
    s += __shfl_xor(s, 1, 64);
    s += __shfl_xor(s, 2, 64);
    s += __shfl_xor(s, 4, 64);
    if (part == 0) scaleS[row] = s + cb2[0];
  }
  for (int idx = t; idx < 16 * 256; idx += 512) {
    const int r = idx >> 8, c = idx & 255;
    float v = 0.f;
    if (r < nvalid) {
      if (c < HD) v = Hin[(size_t)(n0 + r) * HD + c];
      else {
        const int col = c - HD;
#pragma unroll
        for (int k = 0; k < KN; ++k) v += bf2f(bufB[swz128(r * KN + k, col)]);
      }
    }
    nodeA[swz256(r, c)] = f2bf(v);
  }
  __syncthreads();

  // ---- P5: NG1 (u = silu([H|agg] @ nW1 + nb1)) ; X update ----
  {
    f32x4 acc = {};
    const short* bp = N1T + (wid * 16 + lr) * 256;
#pragma unroll
    for (int ks = 0; ks < 8; ++ks) {
      const int k0 = ks * 32 + lk * 8;
      const short8 a = *(const short8*)&nodeA[swz256(lr, k0)];
      const short8 b = *(const short8*)(bp + k0);
      acc = mfma16(a, b, acc);
    }
    const int col = wid * 16 + lr;
    const float bias = nb1[col];
#pragma unroll
    for (int g = 0; g < 4; ++g)
      uT[swz128(lk * 4 + g, col)] = f2bf(silu_f(acc[g] + bias));
  }
  {
    float* XiSf = &XiS[0][0];
    for (int idx = t; idx < NPB * XD; idx += 512) {
      const int nd = idx / XD, e = idx - nd * XD;
      if (nd < nvalid) {
        const float xi = XiSf[idx];
        float a = 0.f;
#pragma unroll
        for (int k = 0; k < KN; ++k) {
          const int r = nd * KN + k;
          a += (xi - Xin[(size_t)nbrS[r] * XD + e]) * scaleS[r];
        }
        Xout[(size_t)(n0 + nd) * XD + e] = xi + a / 9.0f;
      }
    }
  }
  __syncthreads();

  // ---- NG2: Hout = Hi + u @ nW2 + nb2 ----
  {
    f32x4 acc = {};
    const short* bp = N2T + (wid * 16 + lr) * 128;
#pragma unroll
    for (int ks = 0; ks < 4; ++ks) {
      const int k0 = ks * 32 + lk * 8;
      const short8 a = *(const short8*)&uT[swz128(lr, k0)];
      const short8 b = *(const short8*)(bp + k0);
      acc = mfma16(a, b, acc);
    }
    const int col = wid * 16 + lr;
    const float bias = nb2[col];
#pragma unroll
    for (int g = 0; g < 4; ++g) {
      const int row = lk * 4 + g;
      if (row < nvalid)
        Hout[(size_t)(n0 + row) * HD + col] =
            Hin[(size_t)(n0 + row) * HD + col] + acc[g] + bias;
    }
  }
}

// ---------------------------------------------------------------------------
// Output head (4-way ILP unroll)
// ---------------------------------------------------------------------------
__global__ __launch_bounds__(128) void out_kernel(
    const float* __restrict__ H, const float* __restrict__ X,
    const float* __restrict__ oW1, const float* __restrict__ ob1,
    const float* __restrict__ oW2, const float* __restrict__ ob2,
    float* __restrict__ out)
{
  __shared__ float hs[HD];
  __shared__ float u[HD];
  const int i = blockIdx.x, j = threadIdx.x;

  hs[j] = silu_f(H[i * HD + j]);
  __syncthreads();
  float a0 = 0.f, a1 = 0.f, a2 = 0.f, a3 = 0.f;
  for (int k = 0; k < HD; k += 4) {
    a0 = fmaf(hs[k + 0], oW1[(k + 0) * HD + j], a0);
    a1 = fmaf(hs[k + 1], oW1[(k + 1) * HD + j], a1);
    a2 = fmaf(hs[k + 2], oW1[(k + 2) * HD + j], a2);
    a3 = fmaf(hs[k + 3], oW1[(k + 3) * HD + j], a3);
  }
  u[j] = silu_f(ob1[j] + ((a0 + a1) + (a2 + a3)));
  __syncthreads();
  if (j < NCLS) {
    float o0 = 0.f, o1 = 0.f, o2 = 0.f, o3 = 0.f;
    for (int k = 0; k < HD; k += 4) {
      o0 = fmaf(u[k + 0], oW2[(k + 0) * NCLS + j], o0);
      o1 = fmaf(u[k + 1], oW2[(k + 1) * NCLS + j], o1);
      o2 = fmaf(u[k + 2], oW2[(k + 2) * NCLS + j], o2);
      o3 = fmaf(u[k + 3], oW2[(k + 3) * NCLS + j], o3);
    }
    out[i * NCLS + j] = ob2[j] + ((o0 + o1) + (o2 + o3));
  }
  if (j < XD) out[NNODE * NCLS + i * XD + j] = X[i * XD + j];
}

// ---------------------------------------------------------------------------
extern "C" void kernel_launch(void* const* d_in, const int* in_sizes, int n_in,
                              void* d_out, int out_size, void* d_ws, size_t ws_size,
                              hipStream_t stream)
{
  const float* X0       = (const float*)d_in[0];
  const int*   S        = (const int*)  d_in[1];
  const float* embed    = (const float*)d_in[3];
  const float* W_in     = (const float*)d_in[4];
  const float* b_in     = (const float*)d_in[5];
  const float* channelw = (const float*)d_in[6];
  const float* eW1      = (const float*)d_in[7];
  const float* eb1      = (const float*)d_in[8];
  const float* eW2      = (const float*)d_in[9];
  const float* eb2      = (const float*)d_in[10];
  const float* cW1      = (const float*)d_in[11];
  const float* cb1      = (const float*)d_in[12];
  const float* cW2      = (const float*)d_in[13];
  const float* cb2      = (const float*)d_in[14];
  const float* nW1      = (const float*)d_in[15];
  const float* nb1      = (const float*)d_in[16];
  const float* nW2      = (const float*)d_in[17];
  const float* nb2      = (const float*)d_in[18];
  const float* mW1      = (const float*)d_in[19];
  const float* mb1      = (const float*)d_in[20];
  const float* mW2      = (const float*)d_in[21];
  const float* mb2      = (const float*)d_in[22];
  const float* oW1      = (const float*)d_in[23];
  const float* ob1      = (const float*)d_in[24];
  const float* oW2      = (const float*)d_in[25];
  const float* ob2      = (const float*)d_in[26];

  char* ws = (char*)d_ws;
  const size_t HBYTES = (size_t)NNODE * HD * sizeof(float);   // 3,145,728
  const size_t XBYTES = (size_t)NNODE * XD * sizeof(float);   // 1,032,192
  float* Hb[2] = { (float*)(ws), (float*)(ws + HBYTES) };
  float* Xb[2] = { (float*)(ws + 2 * HBYTES), (float*)(ws + 2 * HBYTES + XBYTES) };
  int*   nbr   = (int*)(ws + 2 * HBYTES + 2 * XBYTES);
  short* Wbf   = (short*)(ws + 2 * HBYTES + 2 * XBYTES + (size_t)NNODE * KN * sizeof(int));
  float* PQ    = (float*)(ws + 2 * HBYTES + 2 * XBYTES + (size_t)NNODE * KN * sizeof(int)
                             + 3 * 114688 * sizeof(short));

  prep_weights<<<dim3(128, 15), 256, 0, stream>>>(eW1, eW2, cW1, nW1, nW2, Wbf);
  copy_kernel<<<(NNODE * XD + 255) / 256, 256, 0, stream>>>(X0, Xb[0], NNODE * XD);

  int hc = 0, xc = 0;
  for (int t = 0; t < 3; ++t) {
    const float* Hmem = (t == 0) ? nullptr : Hb[hc];
    h_init_kernel<<<NNODE, HD, 0, stream>>>(embed, S, W_in, b_in, Hmem,
                                            mW1, mb1, mW2, mb2, Hb[hc ^ 1]);
    hc ^= 1;
    knn_kernel<<<NNODE / 4, 256, 0, stream>>>(Xb[xc], nbr);
    for (int l = 0; l < 3; ++l) {
      const short* Wl = Wbf + (size_t)l * 114688;
      pq_kernel<<<NNODE / 32, 512, 0, stream>>>(Hb[hc], Wl, PQ);
      edge_layer_kernel<<<EDGE_BLOCKS, 512, 0, stream>>>(
          Hb[hc], Hb[hc ^ 1], Xb[xc], Xb[xc ^ 1], nbr, channelw, PQ,
          eW1 + (size_t)l * 257 * HD, eb1 + (size_t)l * HD,
          eb2 + (size_t)l * HD,  cb1 + (size_t)l * HD,
          cW2 + (size_t)l * HD,  cb2 + (size_t)l,
          nb1 + (size_t)l * HD,  nb2 + (size_t)l * HD,
          Wl + 32768, Wl + 49152, Wl + 65536, Wl + 98304);
      hc ^= 1; xc ^= 1;
    }
  }
  out_kernel<<<NNODE, HD, 0, stream>>>(Hb[hc], Xb[xc], oW1, ob1, oW2, ob2, (float*)d_out);
}

// Round 4
// 610.106 us; speedup vs baseline: 2.9439x; 1.0922x over previous
//
#include <hip/hip_runtime.h>
#include <math.h>

// ---- problem constants ----
#define NNODE 6144
#define SEG   512
#define NCH   14
#define XD    42          // NCH*3
#define ED    64          // embed dim
#define HD    128
#define NCLS  25
#define KN    9
#define NPB   7           // nodes per edge-block
#define ROWS  64          // NPB*KN = 63, padded to 64
#define EDGE_BLOCKS ((NNODE + NPB - 1) / NPB)

typedef __attribute__((ext_vector_type(8))) short short8;
typedef __attribute__((ext_vector_type(4))) short short4v;
typedef __attribute__((ext_vector_type(4))) float f32x4;

__device__ __forceinline__ float silu_f(float x) {
  return x / (1.0f + __expf(-x));
}
// bf16 round-nearest-even convert (finite inputs only)
__device__ __forceinline__ short f2bf(float x) {
  unsigned u = __builtin_bit_cast(unsigned, x);
  unsigned r = (u + 0x7fffu + ((u >> 16) & 1u)) >> 16;
  return (short)r;
}
__device__ __forceinline__ float bf2f(short s) {
  unsigned u = ((unsigned)(unsigned short)s) << 16;
  return __builtin_bit_cast(float, u);
}
__device__ __forceinline__ f32x4 mfma16(short8 a, short8 b, f32x4 c) {
  return __builtin_amdgcn_mfma_f32_16x16x32_bf16(a, b, c, 0, 0, 0);
}
// XOR swizzle: rows of 128 (or 256) bf16 elems; flip byte bits 4..6 by row&7
__device__ __forceinline__ int swz128(int row, int col) {
  return row * 128 + (col ^ ((row & 7) << 3));
}
__device__ __forceinline__ int swz256(int row, int col) {
  return row * 256 + (col ^ ((row & 7) << 3));
}

// ---------------------------------------------------------------------------
// weight prep: bf16 [N][K] transposed copies of the 5 GEMM weights, per layer
// ---------------------------------------------------------------------------
__global__ __launch_bounds__(256) void prep_weights(
    const float* __restrict__ eW1, const float* __restrict__ eW2,
    const float* __restrict__ cW1, const float* __restrict__ nW1,
    const float* __restrict__ nW2, short* __restrict__ out)
{
  const int mat = blockIdx.y % 5, l = blockIdx.y / 5;
  const int idx = blockIdx.x * 256 + threadIdx.x;
  const int K = (mat == 0 || mat == 3) ? 256 : 128;
  if (idx >= K * 128) return;
  const int n = idx / K, k = idx - n * K;
  const float* src;
  switch (mat) {
    case 0: src = eW1 + (size_t)l * 257 * 128; break;   // rows 0..255 (radial row fp32)
    case 1: src = eW2 + (size_t)l * 128 * 128; break;
    case 2: src = cW1 + (size_t)l * 128 * 128; break;
    case 3: src = nW1 + (size_t)l * 256 * 128; break;
    default: src = nW2 + (size_t)l * 128 * 128; break;
  }
  const int dofs[5] = {0, 32768, 49152, 65536, 98304};
  out[(size_t)l * 114688 + dofs[mat] + idx] = f2bf(src[k * 128 + n]);
}

// ---------------------------------------------------------------------------
__global__ void copy_kernel(const float* __restrict__ src, float* __restrict__ dst, int n) {
  int i = blockIdx.x * blockDim.x + threadIdx.x;
  if (i < n) dst[i] = src[i];
}

// ---------------------------------------------------------------------------
// pq_kernel: PQ[i][c] = sum_k H[i][k] * (c<128 ? eW1[k][c] : eW1[128+k][c-128])
// 32 rows per block, 512 threads (8 waves), fp32 output.
// ---------------------------------------------------------------------------
__global__ __launch_bounds__(512) void pq_kernel(
    const float* __restrict__ Hin, const short* __restrict__ W1T,
    float* __restrict__ PQ)
{
  __shared__ __align__(16) short A[32 * HD];
  const int t = threadIdx.x;
  const int m0 = blockIdx.x * 32;

  const float4* H4 = (const float4*)(Hin + (size_t)m0 * HD);
  for (int idx = t; idx < 32 * 32; idx += 512) {
    const int r = idx >> 5, c4 = idx & 31;
    float4 v = H4[r * 32 + c4];
    short4v s;
    s.x = f2bf(v.x); s.y = f2bf(v.y); s.z = f2bf(v.z); s.w = f2bf(v.w);
    *(short4v*)&A[swz128(r, c4 * 4)] = s;
  }
  __syncthreads();

  const int wid = t >> 6, lane = t & 63;
  const int lr = lane & 15, lk = lane >> 4;
  const int mt = wid >> 2;            // m-tile 0..1
  const int nb = (wid & 3) * 4;       // first of 4 n-tiles
  const int rA = mt * 16 + lr;

  f32x4 acc[4] = {};
#pragma unroll
  for (int ks = 0; ks < 4; ++ks) {
    const int k0 = ks * 32 + lk * 8;
    const short8 a = *(const short8*)&A[swz128(rA, k0)];
#pragma unroll
    for (int ni = 0; ni < 4; ++ni) {
      const int c = (nb + ni) * 16 + lr;
      const short* bp = (c < HD) ? (W1T + c * 256 + k0)
                                 : (W1T + (c - HD) * 256 + HD + k0);
      const short8 b = *(const short8*)bp;
      acc[ni] = mfma16(a, b, acc[ni]);
    }
  }
#pragma unroll
  for (int ni = 0; ni < 4; ++ni) {
    const int c = (nb + ni) * 16 + lr;
#pragma unroll
    for (int g = 0; g < 4; ++g) {
      const int row = mt * 16 + lk * 4 + g;
      PQ[(size_t)(m0 + row) * 256 + c] = acc[ni][g];
    }
  }
}

// ---------------------------------------------------------------------------
// H init: H = (embed[S] [+ mem-MLP(Hmem)]) @ W_in + b_in  (4-way ILP unroll)
// ---------------------------------------------------------------------------
__global__ __launch_bounds__(128) void h_init_kernel(
    const float* __restrict__ embed, const int* __restrict__ S,
    const float* __restrict__ W_in, const float* __restrict__ b_in,
    const float* __restrict__ Hmem,
    const float* __restrict__ mW1, const float* __restrict__ mb1,
    const float* __restrict__ mW2, const float* __restrict__ mb2,
    float* __restrict__ Hout)
{
  __shared__ float a1[HD];
  __shared__ float a2[HD];
  __shared__ float h0[ED];
  const int i = blockIdx.x, j = threadIdx.x;

  if (Hmem) {
    a1[j] = silu_f(Hmem[i * HD + j]);
    __syncthreads();
    float m0 = 0.f, m1 = 0.f, m2 = 0.f, m3 = 0.f;
    for (int k = 0; k < HD; k += 4) {
      m0 = fmaf(a1[k + 0], mW1[(k + 0) * HD + j], m0);
      m1 = fmaf(a1[k + 1], mW1[(k + 1) * HD + j], m1);
      m2 = fmaf(a1[k + 2], mW1[(k + 2) * HD + j], m2);
      m3 = fmaf(a1[k + 3], mW1[(k + 3) * HD + j], m3);
    }
    a2[j] = silu_f(mb1[j] + ((m0 + m1) + (m2 + m3)));
    __syncthreads();
    if (j < ED) {
      float v0 = 0.f, v1 = 0.f, v2 = 0.f, v3 = 0.f;
      for (int k = 0; k < HD; k += 4) {
        v0 = fmaf(a2[k + 0], mW2[(k + 0) * ED + j], v0);
        v1 = fmaf(a2[k + 1], mW2[(k + 1) * ED + j], v1);
        v2 = fmaf(a2[k + 2], mW2[(k + 2) * ED + j], v2);
        v3 = fmaf(a2[k + 3], mW2[(k + 3) * ED + j], v3);
      }
      h0[j] = embed[S[i] * ED + j] + mb2[j] + ((v0 + v1) + (v2 + v3));
    }
  } else {
    if (j < ED) h0[j] = embed[S[i] * ED + j];
  }
  __syncthreads();
  float h0a = 0.f, h1a = 0.f, h2a = 0.f, h3a = 0.f;
  for (int k = 0; k < ED; k += 4) {
    h0a = fmaf(h0[k + 0], W_in[(k + 0) * HD + j], h0a);
    h1a = fmaf(h0[k + 1], W_in[(k + 1) * HD + j], h1a);
    h2a = fmaf(h0[k + 2], W_in[(k + 2) * HD + j], h2a);
    h3a = fmaf(h0[k + 3], W_in[(k + 3) * HD + j], h3a);
  }
  Hout[i * HD + j] = b_in[j] + ((h0a + h1a) + (h2a + h3a));
}

// ---------------------------------------------------------------------------
// kNN: one wave per node, candidates in registers, zero barriers/LDS.
// ---------------------------------------------------------------------------
__global__ __launch_bounds__(256) void knn_kernel(const float* __restrict__ X,
                                                  int* __restrict__ nbr)
{
  const int w = threadIdx.x >> 6, lane = threadIdx.x & 63;
  const int i = blockIdx.x * 4 + w;
  const int base = (i / SEG) * SEG;

  const float cx = X[i * XD + 3], cy = X[i * XD + 4], cz = X[i * XD + 5];
  float dv[8];
  int   di[8];
#pragma unroll
  for (int q = 0; q < 8; ++q) {
    const int j = base + lane + q * 64;
    float dx = __fsub_rn(cx, X[j * XD + 3]);
    float dy = __fsub_rn(cy, X[j * XD + 4]);
    float dz = __fsub_rn(cz, X[j * XD + 5]);
    float d2 = __fadd_rn(__fadd_rn(__fmul_rn(dx, dx), __fmul_rn(dy, dy)), __fmul_rn(dz, dz));
    if (j == i) d2 = 1e9f;
    dv[q] = d2; di[q] = j;
  }
  for (int it = 0; it < KN; ++it) {
    float bv = dv[0]; int bi = di[0];
#pragma unroll
    for (int q = 1; q < 8; ++q)
      if (dv[q] < bv || (dv[q] == bv && di[q] < bi)) { bv = dv[q]; bi = di[q]; }
#pragma unroll
    for (int m = 1; m < 64; m <<= 1) {
      float ov = __shfl_xor(bv, m, 64);
      int   oi = __shfl_xor(bi, m, 64);
      if (ov < bv || (ov == bv && oi < bi)) { bv = ov; bi = oi; }
    }
    if (lane == 0) nbr[i * KN + it] = bi;
    const int rel = bi - base;
    const int oq = rel >> 6;
#pragma unroll
    for (int q = 0; q < 8; ++q)
      if (q == oq && (rel & 63) == lane) dv[q] = 3e38f;
  }
}

// ---------------------------------------------------------------------------
// Fused per-layer edge kernel (factored GEMM1 via PQ).
// 7 nodes (63 edges -> 64 rows) per block, 512 threads = 8 waves.
// LDS ~39.8 KB -> 4 blocks/CU; all 878 blocks co-resident (no tail).
// Phase P01 fuses nbr-load + radial (8 thr/row, shfl-reduce) + h1 build.
// ---------------------------------------------------------------------------
__global__ __launch_bounds__(512, 8) void edge_layer_kernel(
    const float* __restrict__ Hin,  float* __restrict__ Hout,
    const float* __restrict__ Xin,  float* __restrict__ Xout,
    const int*   __restrict__ nbr,  const float* __restrict__ channel_w,
    const float* __restrict__ PQ,
    const float* __restrict__ eW1,  const float* __restrict__ eb1,
    const float* __restrict__ eb2,  const float* __restrict__ cb1,
    const float* __restrict__ cW2,  const float* __restrict__ cb2,
    const float* __restrict__ nb1,  const float* __restrict__ nb2,
    const short* __restrict__ W2T,  const short* __restrict__ C1T,
    const short* __restrict__ N1T,  const short* __restrict__ N2T)
{
  __shared__ __align__(16) short bufA[ROWS * HD];   // h1, then s1     (16 KB)
  __shared__ __align__(16) short bufB[ROWS * HD];   // msg             (16 KB)
  __shared__ __align__(16) short nodeA[NPB * 256];  // [Hi | agg]      (3.5 KB)
  __shared__ __align__(16) short uT[NPB * HD];      // node hidden     (1.75 KB)
  __shared__ float XiS[NPB][XD];
  __shared__ float scaleS[ROWS];
  __shared__ int   nbrS[ROWS];

  const int t  = threadIdx.x;
  const int n0 = blockIdx.x * NPB;
  const int nvalid = (NNODE - n0 < NPB) ? (NNODE - n0) : NPB;
  const int evalid = nvalid * KN;

  // ---- P01: nbr + radial (8 thr/row, shuffle-reduced) + h1 + staging ----
  {
    const int row  = t >> 3;          // 0..63
    const int part = t & 7;           // 0..7
    const bool rvalid = row < evalid;
    const int nd = row / KN;
    const int jn = rvalid ? nbr[n0 * KN + row] : n0;
    if (part == 0) nbrS[row] = jn;

    float r = 0.f;
    if (rvalid) {
      const float* xi = Xin + (size_t)(n0 + nd) * XD;
      const float* xj = Xin + (size_t)jn * XD;
      {
        const int c = part;
        float dx = xi[c * 3 + 0] - xj[c * 3 + 0];
        float dy = xi[c * 3 + 1] - xj[c * 3 + 1];
        float dz = xi[c * 3 + 2] - xj[c * 3 + 2];
        r += channel_w[c] * (dx * dx + dy * dy + dz * dz);
      }
      if (part < 6) {
        const int c = part + 8;
        float dx = xi[c * 3 + 0] - xj[c * 3 + 0];
        float dy = xi[c * 3 + 1] - xj[c * 3 + 1];
        float dz = xi[c * 3 + 2] - xj[c * 3 + 2];
        r += channel_w[c] * (dx * dx + dy * dy + dz * dz);
      }
    }
    r += __shfl_xor(r, 1, 64);
    r += __shfl_xor(r, 2, 64);
    r += __shfl_xor(r, 4, 64);

    // staging: Xi (fp32) and the Hi half of nodeA (bf16)
    {
      float* XiSf = &XiS[0][0];
      for (int idx = t; idx < NPB * XD; idx += 512) {
        const int nd2 = idx / XD;
        XiSf[idx] = (nd2 < nvalid) ? Xin[n0 * XD + idx] : 0.f;
      }
      for (int idx = t; idx < NPB * HD; idx += 512) {
        const int r2 = idx >> 7, c = idx & 127;
        const float v = (r2 < nvalid) ? Hin[(size_t)(n0 + r2) * HD + c] : 0.f;
        nodeA[swz256(r2, c)] = f2bf(v);
      }
    }

    // h1 = silu(P[i] + Q[j] + radial*w256 + eb1) -> bufA (this thread: 4 c4)
    const int inode = n0 + ((nd < nvalid) ? nd : 0);
    const float4* PQ4 = (const float4*)PQ;
    const float4* w2564 = (const float4*)(eW1 + 256 * HD);
    const float4* eb14 = (const float4*)eb1;
#pragma unroll
    for (int ii = 0; ii < 4; ++ii) {
      const int c4 = part + ii * 8;
      const float4 p = PQ4[(size_t)inode * 64 + c4];
      const float4 q = PQ4[(size_t)jn * 64 + 32 + c4];
      const float4 w = w2564[c4];
      const float4 bb = eb14[c4];
      short4v s;
      s.x = f2bf(silu_f(p.x + q.x + r * w.x + bb.x));
      s.y = f2bf(silu_f(p.y + q.y + r * w.y + bb.y));
      s.z = f2bf(silu_f(p.z + q.z + r * w.z + bb.z));
      s.w = f2bf(silu_f(p.w + q.w + r * w.w + bb.w));
      *(short4v*)&bufA[swz128(row, c4 * 4)] = s;
    }
  }
  __syncthreads();

  const int wid  = t >> 6;       // 0..7
  const int lane = t & 63;
  const int m2 = wid >> 2;       // 0..1
  const int n2 = wid & 3;        // 0..3
  const int lr = lane & 15;
  const int lk = lane >> 4;
  const int rA0 = (m2 * 2) * 16 + lr;
  const int rA1 = rA0 + 16;

  // ---- G2: msg = silu(h1 @ eW2 + eb2) -> bufB ----
  {
    f32x4 acc[2][2] = {};
    const short* b0p = W2T + ((n2 * 2) * 16 + lr) * 128;
    const short* b1p = b0p + 16 * 128;
#pragma unroll
    for (int ks = 0; ks < 4; ++ks) {
      const int k0 = ks * 32 + lk * 8;
      const short8 a0 = *(const short8*)&bufA[swz128(rA0, k0)];
      const short8 a1 = *(const short8*)&bufA[swz128(rA1, k0)];
      const short8 b0 = *(const short8*)(b0p + k0);
      const short8 b1 = *(const short8*)(b1p + k0);
      acc[0][0] = mfma16(a0, b0, acc[0][0]);
      acc[0][1] = mfma16(a0, b1, acc[0][1]);
      acc[1][0] = mfma16(a1, b0, acc[1][0]);
      acc[1][1] = mfma16(a1, b1, acc[1][1]);
    }
#pragma unroll
    for (int ni = 0; ni < 2; ++ni) {
      const int col = (n2 * 2 + ni) * 16 + lr;
      const float bias = eb2[col];
#pragma unroll
      for (int mi = 0; mi < 2; ++mi) {
        const int rb = (m2 * 2 + mi) * 16 + lk * 4;
#pragma unroll
        for (int g = 0; g < 4; ++g)
          bufB[swz128(rb + g, col)] = f2bf(silu_f(acc[mi][ni][g] + bias));
      }
    }
  }
  __syncthreads();

  // ---- G3: s1 = silu(msg @ cW1 + cb1) -> bufA ----
  {
    f32x4 acc[2][2] = {};
    const short* b0p = C1T + ((n2 * 2) * 16 + lr) * 128;
    const short* b1p = b0p + 16 * 128;
#pragma unroll
    for (int ks = 0; ks < 4; ++ks) {
      const int k0 = ks * 32 + lk * 8;
      const short8 a0 = *(const short8*)&bufB[swz128(rA0, k0)];
      const short8 a1 = *(const short8*)&bufB[swz128(rA1, k0)];
      const short8 b0 = *(const short8*)(b0p + k0);
      const short8 b1 = *(const short8*)(b1p + k0);
      acc[0][0] = mfma16(a0, b0, acc[0][0]);
      acc[0][1] = mfma16(a0, b1, acc[0][1]);
      acc[1][0] = mfma16(a1, b0, acc[1][0]);
      acc[1][1] = mfma16(a1, b1, acc[1][1]);
    }
#pragma unroll
    for (int ni = 0; ni < 2; ++ni) {
      const int col = (n2 * 2 + ni) * 16 + lr;
      const float bias = cb1[col];
#pragma unroll
      for (int mi = 0; mi < 2; ++mi) {
        const int rb = (m2 * 2 + mi) * 16 + lk * 4;
#pragma unroll
        for (int g = 0; g < 4; ++g)
          bufA[swz128(rb + g, col)] = f2bf(silu_f(acc[mi][ni][g] + bias));
      }
    }
  }
  __syncthreads();

  // ---- P4: scale (8 thr/row shuffle-reduce) ; nodeA agg half ----
  {
    const int row = t >> 3, part = t & 7;
    float s = 0.f;
#pragma unroll
    for (int qq = 0; qq < 16; ++qq) {
      const int k = part * 16 + qq;
      s = fmaf(bf2f(bufA[swz128(row, k)]), cW2[k], s);
    }
    s += __shfl_xor(s, 1, 64);
    s += __shfl_xor(s, 2, 64);
    s += __shfl_xor(s, 4, 64);
    if (part == 0) scaleS[row] = s + cb2[0];
  }
  for (int idx = t; idx < NPB * HD; idx += 512) {
    const int r2 = idx >> 7, col = idx & 127;
    float v = 0.f;
    if (r2 < nvalid) {
#pragma unroll
      for (int k = 0; k < KN; ++k) v += bf2f(bufB[swz128(r2 * KN + k, col)]);
    }
    nodeA[swz256(r2, col + HD)] = f2bf(v);
  }
  __syncthreads();

  // ---- P5: NG1 (u = silu([H|agg] @ nW1 + nb1)) ; X update ----
  {
    f32x4 acc = {};
    const short* bp = N1T + (wid * 16 + lr) * 256;
#pragma unroll
    for (int ks = 0; ks < 8; ++ks) {
      const int k0 = ks * 32 + lk * 8;
      short8 a = {0, 0, 0, 0, 0, 0, 0, 0};
      if (lr < NPB) a = *(const short8*)&nodeA[swz256(lr, k0)];
      const short8 b = *(const short8*)(bp + k0);
      acc = mfma16(a, b, acc);
    }
    const int col = wid * 16 + lr;
    const float bias = nb1[col];
#pragma unroll
    for (int g = 0; g < 4; ++g) {
      const int orow = lk * 4 + g;
      if (orow < NPB) uT[swz128(orow, col)] = f2bf(silu_f(acc[g] + bias));
    }
  }
  {
    float* XiSf = &XiS[0][0];
    for (int idx = t; idx < NPB * XD; idx += 512) {
      const int nd = idx / XD, e = idx - nd * XD;
      if (nd < nvalid) {
        const float xi = XiSf[idx];
        float a = 0.f;
#pragma unroll
        for (int k = 0; k < KN; ++k) {
          const int r = nd * KN + k;
          a += (xi - Xin[(size_t)nbrS[r] * XD + e]) * scaleS[r];
        }
        Xout[(size_t)(n0 + nd) * XD + e] = xi + a / 9.0f;
      }
    }
  }
  __syncthreads();

  // ---- NG2: Hout = Hi + u @ nW2 + nb2 ----
  {
    f32x4 acc = {};
    const short* bp = N2T + (wid * 16 + lr) * 128;
#pragma unroll
    for (int ks = 0; ks < 4; ++ks) {
      const int k0 = ks * 32 + lk * 8;
      short8 a = {0, 0, 0, 0, 0, 0, 0, 0};
      if (lr < NPB) a = *(const short8*)&uT[swz128(lr, k0)];
      const short8 b = *(const short8*)(bp + k0);
      acc = mfma16(a, b, acc);
    }
    const int col = wid * 16 + lr;
    const float bias = nb2[col];
#pragma unroll
    for (int g = 0; g < 4; ++g) {
      const int row = lk * 4 + g;
      if (row < nvalid)
        Hout[(size_t)(n0 + row) * HD + col] =
            Hin[(size_t)(n0 + row) * HD + col] + acc[g] + bias;
    }
  }
}

// ---------------------------------------------------------------------------
// Output head (4-way ILP unroll)
// ---------------------------------------------------------------------------
__global__ __launch_bounds__(128) void out_kernel(
    const float* __restrict__ H, const float* __restrict__ X,
    const float* __restrict__ oW1, const float* __restrict__ ob1,
    const float* __restrict__ oW2, const float* __restrict__ ob2,
    float* __restrict__ out)
{
  __shared__ float hs[HD];
  __shared__ float u[HD];
  const int i = blockIdx.x, j = threadIdx.x;

  hs[j] = silu_f(H[i * HD + j]);
  __syncthreads();
  float a0 = 0.f, a1 = 0.f, a2 = 0.f, a3 = 0.f;
  for (int k = 0; k < HD; k += 4) {
    a0 = fmaf(hs[k + 0], oW1[(k + 0) * HD + j], a0);
    a1 = fmaf(hs[k + 1], oW1[(k + 1) * HD + j], a1);
    a2 = fmaf(hs[k + 2], oW1[(k + 2) * HD + j], a2);
    a3 = fmaf(hs[k + 3], oW1[(k + 3) * HD + j], a3);
  }
  u[j] = silu_f(ob1[j] + ((a0 + a1) + (a2 + a3)));
  __syncthreads();
  if (j < NCLS) {
    float o0 = 0.f, o1 = 0.f, o2 = 0.f, o3 = 0.f;
    for (int k = 0; k < HD; k += 4) {
      o0 = fmaf(u[k + 0], oW2[(k + 0) * NCLS + j], o0);
      o1 = fmaf(u[k + 1], oW2[(k + 1) * NCLS + j], o1);
      o2 = fmaf(u[k + 2], oW2[(k + 2) * NCLS + j], o2);
      o3 = fmaf(u[k + 3], oW2[(k + 3) * NCLS + j], o3);
    }
    out[i * NCLS + j] = ob2[j] + ((o0 + o1) + (o2 + o3));
  }
  if (j < XD) out[NNODE * NCLS + i * XD + j] = X[i * XD + j];
}

// ---------------------------------------------------------------------------
extern "C" void kernel_launch(void* const* d_in, const int* in_sizes, int n_in,
                              void* d_out, int out_size, void* d_ws, size_t ws_size,
                              hipStream_t stream)
{
  const float* X0       = (const float*)d_in[0];
  const int*   S        = (const int*)  d_in[1];
  const float* embed    = (const float*)d_in[3];
  const float* W_in     = (const float*)d_in[4];
  const float* b_in     = (const float*)d_in[5];
  const float* channelw = (const float*)d_in[6];
  const float* eW1      = (const float*)d_in[7];
  const float* eb1      = (const float*)d_in[8];
  const float* eW2      = (const float*)d_in[9];
  const float* eb2      = (const float*)d_in[10];
  const float* cW1      = (const float*)d_in[11];
  const float* cb1      = (const float*)d_in[12];
  const float* cW2      = (const float*)d_in[13];
  const float* cb2      = (const float*)d_in[14];
  const float* nW1      = (const float*)d_in[15];
  const float* nb1      = (const float*)d_in[16];
  const float* nW2      = (const float*)d_in[17];
  const float* nb2      = (const float*)d_in[18];
  const float* mW1      = (const float*)d_in[19];
  const float* mb1      = (const float*)d_in[20];
  const float* mW2      = (const float*)d_in[21];
  const float* mb2      = (const float*)d_in[22];
  const float* oW1      = (const float*)d_in[23];
  const float* ob1      = (const float*)d_in[24];
  const float* oW2      = (const float*)d_in[25];
  const float* ob2      = (const float*)d_in[26];

  char* ws = (char*)d_ws;
  const size_t HBYTES = (size_t)NNODE * HD * sizeof(float);   // 3,145,728
  const size_t XBYTES = (size_t)NNODE * XD * sizeof(float);   // 1,032,192
  float* Hb[2] = { (float*)(ws), (float*)(ws + HBYTES) };
  float* Xb[2] = { (float*)(ws + 2 * HBYTES), (float*)(ws + 2 * HBYTES + XBYTES) };
  int*   nbr   = (int*)(ws + 2 * HBYTES + 2 * XBYTES);
  short* Wbf   = (short*)(ws + 2 * HBYTES + 2 * XBYTES + (size_t)NNODE * KN * sizeof(int));
  float* PQ    = (float*)(ws + 2 * HBYTES + 2 * XBYTES + (size_t)NNODE * KN * sizeof(int)
                             + 3 * 114688 * sizeof(short));

  prep_weights<<<dim3(128, 15), 256, 0, stream>>>(eW1, eW2, cW1, nW1, nW2, Wbf);
  copy_kernel<<<(NNODE * XD + 255) / 256, 256, 0, stream>>>(X0, Xb[0], NNODE * XD);

  int hc = 0, xc = 0;
  for (int t = 0; t < 3; ++t) {
    const float* Hmem = (t == 0) ? nullptr : Hb[hc];
    h_init_kernel<<<NNODE, HD, 0, stream>>>(embed, S, W_in, b_in, Hmem,
                                            mW1, mb1, mW2, mb2, Hb[hc ^ 1]);
    hc ^= 1;
    knn_kernel<<<NNODE / 4, 256, 0, stream>>>(Xb[xc], nbr);
    for (int l = 0; l < 3; ++l) {
      const short* Wl = Wbf + (size_t)l * 114688;
      pq_kernel<<<NNODE / 32, 512, 0, stream>>>(Hb[hc], Wl, PQ);
      edge_layer_kernel<<<EDGE_BLOCKS, 512, 0, stream>>>(
          Hb[hc], Hb[hc ^ 1], Xb[xc], Xb[xc ^ 1], nbr, channelw, PQ,
          eW1 + (size_t)l * 257 * HD, eb1 + (size_t)l * HD,
          eb2 + (size_t)l * HD,  cb1 + (size_t)l * HD,
          cW2 + (size_t)l * HD,  cb2 + (size_t)l,
          nb1 + (size_t)l * HD,  nb2 + (size_t)l * HD,
          Wl + 32768, Wl + 49152, Wl + 65536, Wl + 98304);
      hc ^= 1; xc ^= 1;
    }
  }
  out_kernel<<<NNODE, HD, 0, stream>>>(Hb[hc], Xb[xc], oW1, ob1, oW2, ob2, (float*)d_out);
}

// Round 5
// 595.466 us; speedup vs baseline: 3.0163x; 1.0246x over previous
//
#include <hip/hip_runtime.h>
#include <math.h>

// ---- problem constants ----
#define NNODE 6144
#define SEG   512
#define NCH   14
#define XD    42          // NCH*3
#define ED    64          // embed dim
#define HD    128
#define NCLS  25
#define KN    9
#define NPB   7           // nodes per edge-block
#define ROWS  64          // NPB*KN = 63, padded to 64
#define EDGE_BLOCKS ((NNODE + NPB - 1) / NPB)

typedef __attribute__((ext_vector_type(8))) short short8;
typedef __attribute__((ext_vector_type(4))) short short4v;
typedef __attribute__((ext_vector_type(4))) float f32x4;

__device__ __forceinline__ float silu_f(float x) {
  return x / (1.0f + __expf(-x));
}
// bf16 round-nearest-even convert (finite inputs only)
__device__ __forceinline__ short f2bf(float x) {
  unsigned u = __builtin_bit_cast(unsigned, x);
  unsigned r = (u + 0x7fffu + ((u >> 16) & 1u)) >> 16;
  return (short)r;
}
__device__ __forceinline__ float bf2f(short s) {
  unsigned u = ((unsigned)(unsigned short)s) << 16;
  return __builtin_bit_cast(float, u);
}
__device__ __forceinline__ f32x4 mfma16(short8 a, short8 b, f32x4 c) {
  return __builtin_amdgcn_mfma_f32_16x16x32_bf16(a, b, c, 0, 0, 0);
}
// XOR swizzle: rows of 128 (or 256) bf16 elems; flip elem bits 3..5 by row&7
__device__ __forceinline__ int swz128(int row, int col) {
  return row * 128 + (col ^ ((row & 7) << 3));
}
__device__ __forceinline__ int swz256(int row, int col) {
  return row * 256 + (col ^ ((row & 7) << 3));
}

// ---------------------------------------------------------------------------
// weight prep: bf16 [N][K] transposed copies of the 5 GEMM weights, per layer
// ---------------------------------------------------------------------------
__global__ __launch_bounds__(256) void prep_weights(
    const float* __restrict__ eW1, const float* __restrict__ eW2,
    const float* __restrict__ cW1, const float* __restrict__ nW1,
    const float* __restrict__ nW2, short* __restrict__ out)
{
  const int mat = blockIdx.y % 5, l = blockIdx.y / 5;
  const int idx = blockIdx.x * 256 + threadIdx.x;
  const int K = (mat == 0 || mat == 3) ? 256 : 128;
  if (idx >= K * 128) return;
  const int n = idx / K, k = idx - n * K;
  const float* src;
  switch (mat) {
    case 0: src = eW1 + (size_t)l * 257 * 128; break;   // rows 0..255 (radial row fp32)
    case 1: src = eW2 + (size_t)l * 128 * 128; break;
    case 2: src = cW1 + (size_t)l * 128 * 128; break;
    case 3: src = nW1 + (size_t)l * 256 * 128; break;
    default: src = nW2 + (size_t)l * 128 * 128; break;
  }
  const int dofs[5] = {0, 32768, 49152, 65536, 98304};
  out[(size_t)l * 114688 + dofs[mat] + idx] = f2bf(src[k * 128 + n]);
}

// ---------------------------------------------------------------------------
__global__ void copy_kernel(const float* __restrict__ src, float* __restrict__ dst, int n) {
  int i = blockIdx.x * blockDim.x + threadIdx.x;
  if (i < n) dst[i] = src[i];
}

// ---------------------------------------------------------------------------
// pq_kernel: PQ[i][c] = sum_k H[i][k] * (c<128 ? eW1[k][c] : eW1[128+k][c-128])
// 16 rows per block (384 blocks), 512 threads; wave w owns 2 n-tiles.
// ---------------------------------------------------------------------------
__global__ __launch_bounds__(512) void pq_kernel(
    const float* __restrict__ Hin, const short* __restrict__ W1T,
    float* __restrict__ PQ)
{
  __shared__ __align__(16) short A[16 * HD];
  const int t = threadIdx.x;
  const int m0 = blockIdx.x * 16;

  {
    const int r = t >> 5, c4 = t & 31;   // 512 threads = 16 rows x 32 float4
    const float4 v = ((const float4*)(Hin + (size_t)m0 * HD))[r * 32 + c4];
    short4v s;
    s.x = f2bf(v.x); s.y = f2bf(v.y); s.z = f2bf(v.z); s.w = f2bf(v.w);
    *(short4v*)&A[swz128(r, c4 * 4)] = s;
  }
  __syncthreads();

  const int wid = t >> 6, lane = t & 63;
  const int lr = lane & 15, lk = lane >> 4;

  f32x4 acc[2] = {};
#pragma unroll
  for (int ks = 0; ks < 4; ++ks) {
    const int k0 = ks * 32 + lk * 8;
    const short8 a = *(const short8*)&A[swz128(lr, k0)];
#pragma unroll
    for (int ni = 0; ni < 2; ++ni) {
      const int c = (wid * 2 + ni) * 16 + lr;
      const short* bp = (c < HD) ? (W1T + c * 256 + k0)
                                 : (W1T + (c - HD) * 256 + HD + k0);
      const short8 b = *(const short8*)bp;
      acc[ni] = mfma16(a, b, acc[ni]);
    }
  }
#pragma unroll
  for (int ni = 0; ni < 2; ++ni) {
    const int c = (wid * 2 + ni) * 16 + lr;
#pragma unroll
    for (int g = 0; g < 4; ++g) {
      const int row = lk * 4 + g;
      PQ[(size_t)(m0 + row) * 256 + c] = acc[ni][g];
    }
  }
}

// ---------------------------------------------------------------------------
// H init: H = (embed[S] [+ mem-MLP(Hmem)]) @ W_in + b_in  (4-way ILP unroll)
// ---------------------------------------------------------------------------
__global__ __launch_bounds__(128) void h_init_kernel(
    const float* __restrict__ embed, const int* __restrict__ S,
    const float* __restrict__ W_in, const float* __restrict__ b_in,
    const float* __restrict__ Hmem,
    const float* __restrict__ mW1, const float* __restrict__ mb1,
    const float* __restrict__ mW2, const float* __restrict__ mb2,
    float* __restrict__ Hout)
{
  __shared__ float a1[HD];
  __shared__ float a2[HD];
  __shared__ float h0[ED];
  const int i = blockIdx.x, j = threadIdx.x;

  if (Hmem) {
    a1[j] = silu_f(Hmem[i * HD + j]);
    __syncthreads();
    float m0 = 0.f, m1 = 0.f, m2 = 0.f, m3 = 0.f;
    for (int k = 0; k < HD; k += 4) {
      m0 = fmaf(a1[k + 0], mW1[(k + 0) * HD + j], m0);
      m1 = fmaf(a1[k + 1], mW1[(k + 1) * HD + j], m1);
      m2 = fmaf(a1[k + 2], mW1[(k + 2) * HD + j], m2);
      m3 = fmaf(a1[k + 3], mW1[(k + 3) * HD + j], m3);
    }
    a2[j] = silu_f(mb1[j] + ((m0 + m1) + (m2 + m3)));
    __syncthreads();
    if (j < ED) {
      float v0 = 0.f, v1 = 0.f, v2 = 0.f, v3 = 0.f;
      for (int k = 0; k < HD; k += 4) {
        v0 = fmaf(a2[k + 0], mW2[(k + 0) * ED + j], v0);
        v1 = fmaf(a2[k + 1], mW2[(k + 1) * ED + j], v1);
        v2 = fmaf(a2[k + 2], mW2[(k + 2) * ED + j], v2);
        v3 = fmaf(a2[k + 3], mW2[(k + 3) * ED + j], v3);
      }
      h0[j] = embed[S[i] * ED + j] + mb2[j] + ((v0 + v1) + (v2 + v3));
    }
  } else {
    if (j < ED) h0[j] = embed[S[i] * ED + j];
  }
  __syncthreads();
  float h0a = 0.f, h1a = 0.f, h2a = 0.f, h3a = 0.f;
  for (int k = 0; k < ED; k += 4) {
    h0a = fmaf(h0[k + 0], W_in[(k + 0) * HD + j], h0a);
    h1a = fmaf(h0[k + 1], W_in[(k + 1) * HD + j], h1a);
    h2a = fmaf(h0[k + 2], W_in[(k + 2) * HD + j], h2a);
    h3a = fmaf(h0[k + 3], W_in[(k + 3) * HD + j], h3a);
  }
  Hout[i * HD + j] = b_in[j] + ((h0a + h1a) + (h2a + h3a));
}

// ---------------------------------------------------------------------------
// kNN: one wave per node, candidates in registers, zero barriers/LDS.
// ---------------------------------------------------------------------------
__global__ __launch_bounds__(256) void knn_kernel(const float* __restrict__ X,
                                                  int* __restrict__ nbr)
{
  const int w = threadIdx.x >> 6, lane = threadIdx.x & 63;
  const int i = blockIdx.x * 4 + w;
  const int base = (i / SEG) * SEG;

  const float cx = X[i * XD + 3], cy = X[i * XD + 4], cz = X[i * XD + 5];
  float dv[8];
  int   di[8];
#pragma unroll
  for (int q = 0; q < 8; ++q) {
    const int j = base + lane + q * 64;
    float dx = __fsub_rn(cx, X[j * XD + 3]);
    float dy = __fsub_rn(cy, X[j * XD + 4]);
    float dz = __fsub_rn(cz, X[j * XD + 5]);
    float d2 = __fadd_rn(__fadd_rn(__fmul_rn(dx, dx), __fmul_rn(dy, dy)), __fmul_rn(dz, dz));
    if (j == i) d2 = 1e9f;
    dv[q] = d2; di[q] = j;
  }
  for (int it = 0; it < KN; ++it) {
    float bv = dv[0]; int bi = di[0];
#pragma unroll
    for (int q = 1; q < 8; ++q)
      if (dv[q] < bv || (dv[q] == bv && di[q] < bi)) { bv = dv[q]; bi = di[q]; }
#pragma unroll
    for (int m = 1; m < 64; m <<= 1) {
      float ov = __shfl_xor(bv, m, 64);
      int   oi = __shfl_xor(bi, m, 64);
      if (ov < bv || (ov == bv && oi < bi)) { bv = ov; bi = oi; }
    }
    if (lane == 0) nbr[i * KN + it] = bi;
    const int rel = bi - base;
    const int oq = rel >> 6;
#pragma unroll
    for (int q = 0; q < 8; ++q)
      if (q == oq && (rel & 63) == lane) dv[q] = 3e38f;
  }
}

// ---------------------------------------------------------------------------
// Fused per-layer edge kernel (factored GEMM1 via PQ).
// 7 nodes (63 edges -> 64 rows) per block, 512 threads = 8 waves.
// 4 internal barriers; scale computed in-register during G3 (no s1 buffer).
// LDS 38.5 KB -> 4 blocks/CU if VGPR <= 64 (no forced bound: avoid spills).
// ---------------------------------------------------------------------------
__global__ __launch_bounds__(512) void edge_layer_kernel(
    const float* __restrict__ Hin,  float* __restrict__ Hout,
    const float* __restrict__ Xin,  float* __restrict__ Xout,
    const int*   __restrict__ nbr,  const float* __restrict__ channel_w,
    const float* __restrict__ PQ,
    const float* __restrict__ eW1,  const float* __restrict__ eb1,
    const float* __restrict__ eb2,  const float* __restrict__ cb1,
    const float* __restrict__ cW2,  const float* __restrict__ cb2,
    const float* __restrict__ nb1,  const float* __restrict__ nb2,
    const short* __restrict__ W2T,  const short* __restrict__ C1T,
    const short* __restrict__ N1T,  const short* __restrict__ N2T)
{
  __shared__ __align__(16) short bufA[ROWS * HD];    // h1            (16 KB)
  __shared__ __align__(16) short bufB[ROWS * HD];    // msg           (16 KB)
  __shared__ __align__(16) short nodeA[NPB * 256];   // [Hi | agg]    (3.5 KB)
  __shared__ __align__(16) short uT[NPB * HD];       // node hidden   (1.75 KB)
  __shared__ float scalePart[ROWS][4];               // per-n2 partials (1 KB)
  __shared__ int   nbrS[ROWS];

  const int t  = threadIdx.x;
  const int n0 = blockIdx.x * NPB;
  const int nvalid = (NNODE - n0 < NPB) ? (NNODE - n0) : NPB;
  const int evalid = nvalid * KN;

  // ---- P01: nbr + radial (8 thr/row, shfl-reduced) + h1 + nodeA-Hi ----
  {
    const int row  = t >> 3;          // 0..63
    const int part = t & 7;           // 0..7
    const bool rvalid = row < evalid;
    const int nd = row / KN;
    const int jn = rvalid ? nbr[n0 * KN + row] : n0;
    if (part == 0) nbrS[row] = jn;

    float r = 0.f;
    if (rvalid) {
      const float* xi = Xin + (size_t)(n0 + nd) * XD;
      const float* xj = Xin + (size_t)jn * XD;
      {
        const int c = part;
        float dx = xi[c * 3 + 0] - xj[c * 3 + 0];
        float dy = xi[c * 3 + 1] - xj[c * 3 + 1];
        float dz = xi[c * 3 + 2] - xj[c * 3 + 2];
        r += channel_w[c] * (dx * dx + dy * dy + dz * dz);
      }
      if (part < 6) {
        const int c = part + 8;
        float dx = xi[c * 3 + 0] - xj[c * 3 + 0];
        float dy = xi[c * 3 + 1] - xj[c * 3 + 1];
        float dz = xi[c * 3 + 2] - xj[c * 3 + 2];
        r += channel_w[c] * (dx * dx + dy * dy + dz * dz);
      }
    }
    r += __shfl_xor(r, 1, 64);
    r += __shfl_xor(r, 2, 64);
    r += __shfl_xor(r, 4, 64);

    // nodeA Hi half (vectorized; 224 threads active)
    if (t < NPB * (HD / 4)) {
      const int r2 = t >> 5, c4 = t & 31;
      float4 v = make_float4(0.f, 0.f, 0.f, 0.f);
      if (r2 < nvalid) v = ((const float4*)Hin)[(size_t)(n0 + r2) * 32 + c4];
      short4v s;
      s.x = f2bf(v.x); s.y = f2bf(v.y); s.z = f2bf(v.z); s.w = f2bf(v.w);
      *(short4v*)&nodeA[swz256(r2, c4 * 4)] = s;
    }

    // h1 = silu(P[i] + Q[j] + radial*w256 + eb1) -> bufA (this thread: 4 c4)
    const int inode = n0 + ((nd < nvalid) ? nd : 0);
    const float4* PQ4 = (const float4*)PQ;
    const float4* w2564 = (const float4*)(eW1 + 256 * HD);
    const float4* eb14 = (const float4*)eb1;
#pragma unroll
    for (int ii = 0; ii < 4; ++ii) {
      const int c4 = part + ii * 8;
      const float4 p = PQ4[(size_t)inode * 64 + c4];
      const float4 q = PQ4[(size_t)jn * 64 + 32 + c4];
      const float4 w = w2564[c4];
      const float4 bb = eb14[c4];
      short4v s;
      s.x = f2bf(silu_f(p.x + q.x + r * w.x + bb.x));
      s.y = f2bf(silu_f(p.y + q.y + r * w.y + bb.y));
      s.z = f2bf(silu_f(p.z + q.z + r * w.z + bb.z));
      s.w = f2bf(silu_f(p.w + q.w + r * w.w + bb.w));
      *(short4v*)&bufA[swz128(row, c4 * 4)] = s;
    }
  }
  __syncthreads();

  const int wid  = t >> 6;       // 0..7
  const int lane = t & 63;
  const int m2 = wid >> 2;       // 0..1
  const int n2 = wid & 3;        // 0..3
  const int lr = lane & 15;
  const int lk = lane >> 4;
  const int rA0 = (m2 * 2) * 16 + lr;
  const int rA1 = rA0 + 16;

  // ---- G2: msg = silu(h1 @ eW2 + eb2) -> bufB ----
  {
    f32x4 acc[2][2] = {};
    const short* b0p = W2T + ((n2 * 2) * 16 + lr) * 128;
    const short* b1p = b0p + 16 * 128;
#pragma unroll
    for (int ks = 0; ks < 4; ++ks) {
      const int k0 = ks * 32 + lk * 8;
      const short8 a0 = *(const short8*)&bufA[swz128(rA0, k0)];
      const short8 a1 = *(const short8*)&bufA[swz128(rA1, k0)];
      const short8 b0 = *(const short8*)(b0p + k0);
      const short8 b1 = *(const short8*)(b1p + k0);
      acc[0][0] = mfma16(a0, b0, acc[0][0]);
      acc[0][1] = mfma16(a0, b1, acc[0][1]);
      acc[1][0] = mfma16(a1, b0, acc[1][0]);
      acc[1][1] = mfma16(a1, b1, acc[1][1]);
    }
#pragma unroll
    for (int ni = 0; ni < 2; ++ni) {
      const int col = (n2 * 2 + ni) * 16 + lr;
      const float bias = eb2[col];
#pragma unroll
      for (int mi = 0; mi < 2; ++mi) {
        const int rb = (m2 * 2 + mi) * 16 + lk * 4;
#pragma unroll
        for (int g = 0; g < 4; ++g)
          bufB[swz128(rb + g, col)] = f2bf(silu_f(acc[mi][ni][g] + bias));
      }
    }
  }
  __syncthreads();

  // ---- G3: s1 = silu(msg @ cW1 + cb1), scale partials in-register;
  //          agg = sum_k msg -> nodeA cols 128.. ----
  {
    f32x4 acc[2][2] = {};
    const short* b0p = C1T + ((n2 * 2) * 16 + lr) * 128;
    const short* b1p = b0p + 16 * 128;
#pragma unroll
    for (int ks = 0; ks < 4; ++ks) {
      const int k0 = ks * 32 + lk * 8;
      const short8 a0 = *(const short8*)&bufB[swz128(rA0, k0)];
      const short8 a1 = *(const short8*)&bufB[swz128(rA1, k0)];
      const short8 b0 = *(const short8*)(b0p + k0);
      const short8 b1 = *(const short8*)(b1p + k0);
      acc[0][0] = mfma16(a0, b0, acc[0][0]);
      acc[0][1] = mfma16(a0, b1, acc[0][1]);
      acc[1][0] = mfma16(a1, b0, acc[1][0]);
      acc[1][1] = mfma16(a1, b1, acc[1][1]);
    }
    // per-lane: p[mi][g] = sum_ni silu(acc+cb1[col]) * cW2[col]
    float p[2][4];
#pragma unroll
    for (int mi = 0; mi < 2; ++mi)
#pragma unroll
      for (int g = 0; g < 4; ++g) p[mi][g] = 0.f;
#pragma unroll
    for (int ni = 0; ni < 2; ++ni) {
      const int col = (n2 * 2 + ni) * 16 + lr;
      const float bias = cb1[col];
      const float wv = cW2[col];
#pragma unroll
      for (int mi = 0; mi < 2; ++mi)
#pragma unroll
        for (int g = 0; g < 4; ++g)
          p[mi][g] = fmaf(silu_f(acc[mi][ni][g] + bias), wv, p[mi][g]);
    }
    // butterfly over the 16-lane lr group
#pragma unroll
    for (int m = 1; m < 16; m <<= 1) {
#pragma unroll
      for (int mi = 0; mi < 2; ++mi)
#pragma unroll
        for (int g = 0; g < 4; ++g)
          p[mi][g] += __shfl_xor(p[mi][g], m, 64);
    }
    if (lr == 0) {
#pragma unroll
      for (int mi = 0; mi < 2; ++mi)
#pragma unroll
        for (int g = 0; g < 4; ++g)
          scalePart[(m2 * 2 + mi) * 16 + lk * 4 + g][n2] = p[mi][g];
    }
  }
  for (int idx = t; idx < NPB * HD; idx += 512) {
    const int r2 = idx >> 7, col = idx & 127;
    float v = 0.f;
    if (r2 < nvalid) {
#pragma unroll
      for (int k = 0; k < KN; ++k) v += bf2f(bufB[swz128(r2 * KN + k, col)]);
    }
    nodeA[swz256(r2, col + HD)] = f2bf(v);
  }
  __syncthreads();

  // ---- P5: NG1 (u = silu([H|agg] @ nW1 + nb1)) ; X update ----
  {
    f32x4 acc = {};
    const short* bp = N1T + (wid * 16 + lr) * 256;
#pragma unroll
    for (int ks = 0; ks < 8; ++ks) {
      const int k0 = ks * 32 + lk * 8;
      short8 a = {0, 0, 0, 0, 0, 0, 0, 0};
      if (lr < NPB) a = *(const short8*)&nodeA[swz256(lr, k0)];
      const short8 b = *(const short8*)(bp + k0);
      acc = mfma16(a, b, acc);
    }
    const int col = wid * 16 + lr;
    const float bias = nb1[col];
#pragma unroll
    for (int g = 0; g < 4; ++g) {
      const int orow = lk * 4 + g;
      if (orow < NPB) uT[swz128(orow, col)] = f2bf(silu_f(acc[g] + bias));
    }
  }
  {
    const float c2 = cb2[0];
    for (int idx = t; idx < NPB * XD; idx += 512) {
      const int nd = idx / XD, e = idx - nd * XD;
      if (nd < nvalid) {
        const float xi = Xin[(size_t)n0 * XD + idx];
        float a = 0.f;
#pragma unroll
        for (int k = 0; k < KN; ++k) {
          const int r = nd * KN + k;
          const float sc = ((scalePart[r][0] + scalePart[r][1])
                          + (scalePart[r][2] + scalePart[r][3])) + c2;
          a += (xi - Xin[(size_t)nbrS[r] * XD + e]) * sc;
        }
        Xout[(size_t)(n0 + nd) * XD + e] = xi + a / 9.0f;
      }
    }
  }
  __syncthreads();

  // ---- NG2: Hout = Hi + u @ nW2 + nb2 ----
  {
    f32x4 acc = {};
    const short* bp = N2T + (wid * 16 + lr) * 128;
#pragma unroll
    for (int ks = 0; ks < 4; ++ks) {
      const int k0 = ks * 32 + lk * 8;
      short8 a = {0, 0, 0, 0, 0, 0, 0, 0};
      if (lr < NPB) a = *(const short8*)&uT[swz128(lr, k0)];
      const short8 b = *(const short8*)(bp + k0);
      acc = mfma16(a, b, acc);
    }
    const int col = wid * 16 + lr;
    const float bias = nb2[col];
#pragma unroll
    for (int g = 0; g < 4; ++g) {
      const int row = lk * 4 + g;
      if (row < nvalid)
        Hout[(size_t)(n0 + row) * HD + col] =
            Hin[(size_t)(n0 + row) * HD + col] + acc[g] + bias;
    }
  }
}

// ---------------------------------------------------------------------------
// Output head (4-way ILP unroll)
// ---------------------------------------------------------------------------
__global__ __launch_bounds__(128) void out_kernel(
    const float* __restrict__ H, const float* __restrict__ X,
    const float* __restrict__ oW1, const float* __restrict__ ob1,
    const float* __restrict__ oW2, const float* __restrict__ ob2,
    float* __restrict__ out)
{
  __shared__ float hs[HD];
  __shared__ float u[HD];
  const int i = blockIdx.x, j = threadIdx.x;

  hs[j] = silu_f(H[i * HD + j]);
  __syncthreads();
  float a0 = 0.f, a1 = 0.f, a2 = 0.f, a3 = 0.f;
  for (int k = 0; k < HD; k += 4) {
    a0 = fmaf(hs[k + 0], oW1[(k + 0) * HD + j], a0);
    a1 = fmaf(hs[k + 1], oW1[(k + 1) * HD + j], a1);
    a2 = fmaf(hs[k + 2], oW1[(k + 2) * HD + j], a2);
    a3 = fmaf(hs[k + 3], oW1[(k + 3) * HD + j], a3);
  }
  u[j] = silu_f(ob1[j] + ((a0 + a1) + (a2 + a3)));
  __syncthreads();
  if (j < NCLS) {
    float o0 = 0.f, o1 = 0.f, o2 = 0.f, o3 = 0.f;
    for (int k = 0; k < HD; k += 4) {
      o0 = fmaf(u[k + 0], oW2[(k + 0) * NCLS + j], o0);
      o1 = fmaf(u[k + 1], oW2[(k + 1) * NCLS + j], o1);
      o2 = fmaf(u[k + 2], oW2[(k + 2) * NCLS + j], o2);
      o3 = fmaf(u[k + 3], oW2[(k + 3) * NCLS + j], o3);
    }
    out[i * NCLS + j] = ob2[j] + ((o0 + o1) + (o2 + o3));
  }
  if (j < XD) out[NNODE * NCLS + i * XD + j] = X[i * XD + j];
}

// ---------------------------------------------------------------------------
extern "C" void kernel_launch(void* const* d_in, const int* in_sizes, int n_in,
                              void* d_out, int out_size, void* d_ws, size_t ws_size,
                              hipStream_t stream)
{
  const float* X0       = (const float*)d_in[0];
  const int*   S        = (const int*)  d_in[1];
  const float* embed    = (const float*)d_in[3];
  const float* W_in     = (const float*)d_in[4];
  const float* b_in     = (const float*)d_in[5];
  const float* channelw = (const float*)d_in[6];
  const float* eW1      = (const float*)d_in[7];
  const float* eb1      = (const float*)d_in[8];
  const float* eW2      = (const float*)d_in[9];
  const float* eb2      = (const float*)d_in[10];
  const float* cW1      = (const float*)d_in[11];
  const float* cb1      = (const float*)d_in[12];
  const float* cW2      = (const float*)d_in[13];
  const float* cb2      = (const float*)d_in[14];
  const float* nW1      = (const float*)d_in[15];
  const float* nb1      = (const float*)d_in[16];
  const float* nW2      = (const float*)d_in[17];
  const float* nb2      = (const float*)d_in[18];
  const float* mW1      = (const float*)d_in[19];
  const float* mb1      = (const float*)d_in[20];
  const float* mW2      = (const float*)d_in[21];
  const float* mb2      = (const float*)d_in[22];
  const float* oW1      = (const float*)d_in[23];
  const float* ob1      = (const float*)d_in[24];
  const float* oW2      = (const float*)d_in[25];
  const float* ob2      = (const float*)d_in[26];

  char* ws = (char*)d_ws;
  const size_t HBYTES = (size_t)NNODE * HD * sizeof(float);   // 3,145,728
  const size_t XBYTES = (size_t)NNODE * XD * sizeof(float);   // 1,032,192
  float* Hb[2] = { (float*)(ws), (float*)(ws + HBYTES) };
  float* Xb[2] = { (float*)(ws + 2 * HBYTES), (float*)(ws + 2 * HBYTES + XBYTES) };
  int*   nbr   = (int*)(ws + 2 * HBYTES + 2 * XBYTES);
  short* Wbf   = (short*)(ws + 2 * HBYTES + 2 * XBYTES + (size_t)NNODE * KN * sizeof(int));
  float* PQ    = (float*)(ws + 2 * HBYTES + 2 * XBYTES + (size_t)NNODE * KN * sizeof(int)
                             + 3 * 114688 * sizeof(short));

  prep_weights<<<dim3(128, 15), 256, 0, stream>>>(eW1, eW2, cW1, nW1, nW2, Wbf);
  copy_kernel<<<(NNODE * XD + 255) / 256, 256, 0, stream>>>(X0, Xb[0], NNODE * XD);

  int hc = 0, xc = 0;
  for (int t = 0; t < 3; ++t) {
    const float* Hmem = (t == 0) ? nullptr : Hb[hc];
    h_init_kernel<<<NNODE, HD, 0, stream>>>(embed, S, W_in, b_in, Hmem,
                                            mW1, mb1, mW2, mb2, Hb[hc ^ 1]);
    hc ^= 1;
    knn_kernel<<<NNODE / 4, 256, 0, stream>>>(Xb[xc], nbr);
    for (int l = 0; l < 3; ++l) {
      const short* Wl = Wbf + (size_t)l * 114688;
      pq_kernel<<<NNODE / 16, 512, 0, stream>>>(Hb[hc], Wl, PQ);
      edge_layer_kernel<<<EDGE_BLOCKS, 512, 0, stream>>>(
          Hb[hc], Hb[hc ^ 1], Xb[xc], Xb[xc ^ 1], nbr, channelw, PQ,
          eW1 + (size_t)l * 257 * HD, eb1 + (size_t)l * HD,
          eb2 + (size_t)l * HD,  cb1 + (size_t)l * HD,
          cW2 + (size_t)l * HD,  cb2 + (size_t)l,
          nb1 + (size_t)l * HD,  nb2 + (size_t)l * HD,
          Wl + 32768, Wl + 49152, Wl + 65536, Wl + 98304);
      hc ^= 1; xc ^= 1;
    }
  }
  out_kernel<<<NNODE, HD, 0, stream>>>(Hb[hc], Xb[xc], oW1, ob1, oW2, ob2, (float*)d_out);
}

// Round 6
// 535.271 us; speedup vs baseline: 3.3555x; 1.1125x over previous
//
#include <hip/hip_runtime.h>
#include <math.h>

// ---- problem constants ----
#define NNODE 6144
#define SEG   512
#define NCH   14
#define XD    42          // NCH*3
#define ED    64          // embed dim
#define HD    128
#define NCLS  25
#define KN    9
#define NPB   7           // nodes per edge-block
#define ROWS  64          // NPB*KN = 63, padded to 64
#define EDGE_BLOCKS ((NNODE + NPB - 1) / NPB)

typedef __attribute__((ext_vector_type(8))) short short8;
typedef __attribute__((ext_vector_type(4))) short short4v;
typedef __attribute__((ext_vector_type(4))) float f32x4;

__device__ __forceinline__ float silu_f(float x) {
  return x / (1.0f + __expf(-x));
}
// bf16 round-nearest-even convert (finite inputs only)
__device__ __forceinline__ short f2bf(float x) {
  unsigned u = __builtin_bit_cast(unsigned, x);
  unsigned r = (u + 0x7fffu + ((u >> 16) & 1u)) >> 16;
  return (short)r;
}
__device__ __forceinline__ float bf2f(short s) {
  unsigned u = ((unsigned)(unsigned short)s) << 16;
  return __builtin_bit_cast(float, u);
}
__device__ __forceinline__ f32x4 mfma16(short8 a, short8 b, f32x4 c) {
  return __builtin_amdgcn_mfma_f32_16x16x32_bf16(a, b, c, 0, 0, 0);
}
// XOR swizzle: flip elem bits 3..5 by row&7 (16B granules)
__device__ __forceinline__ int swz128(int row, int col) {
  return row * 128 + (col ^ ((row & 7) << 3));
}
__device__ __forceinline__ int swz256(int row, int col) {
  return row * 256 + (col ^ ((row & 7) << 3));
}
__device__ __forceinline__ int swz64(int row, int col) {
  return row * 64 + (col ^ ((row & 7) << 3));
}

// Wbf layout (shorts): per layer l: l*114688 + {0:eW1T[128n][256k], 32768:eW2T,
// 49152:cW1T, 65536:nW1T[128n][256k], 98304:nW2T}; extras at EXOFF:
// mW1T[128n][128k], +16384 mW2T[64n][128k], +24576 W_inT[128n][64k]
#define EXOFF 344064
#define WBF_SHORTS (EXOFF + 32768)

// ---------------------------------------------------------------------------
// weight prep: bf16 [N][K] transposed copies of all GEMM weights
// ---------------------------------------------------------------------------
__global__ __launch_bounds__(256) void prep_weights(
    const float* __restrict__ eW1, const float* __restrict__ eW2,
    const float* __restrict__ cW1, const float* __restrict__ nW1,
    const float* __restrict__ nW2, const float* __restrict__ mW1,
    const float* __restrict__ mW2, const float* __restrict__ W_in,
    short* __restrict__ out)
{
  const int idx = blockIdx.x * 256 + threadIdx.x;
  if (blockIdx.y == 15) {
    if (idx < 16384) {                       // mW1T [128][128]
      const int n = idx >> 7, k = idx & 127;
      out[EXOFF + idx] = f2bf(mW1[k * HD + n]);
    } else if (idx < 24576) {                // mW2T [64][128]
      const int local = idx - 16384;
      const int n = local >> 7, k = local & 127;
      out[EXOFF + 16384 + local] = f2bf(mW2[k * ED + n]);
    } else if (idx < 32768) {                // W_inT [128][64]
      const int local = idx - 24576;
      const int n = local >> 6, k = local & 63;
      out[EXOFF + 24576 + local] = f2bf(W_in[k * HD + n]);
    }
    return;
  }
  const int mat = blockIdx.y % 5, l = blockIdx.y / 5;
  const int K = (mat == 0 || mat == 3) ? 256 : 128;
  if (idx >= K * 128) return;
  const int n = idx / K, k = idx - n * K;
  const float* src;
  switch (mat) {
    case 0: src = eW1 + (size_t)l * 257 * 128; break;   // rows 0..255 (radial row fp32)
    case 1: src = eW2 + (size_t)l * 128 * 128; break;
    case 2: src = cW1 + (size_t)l * 128 * 128; break;
    case 3: src = nW1 + (size_t)l * 256 * 128; break;
    default: src = nW2 + (size_t)l * 128 * 128; break;
  }
  const int dofs[5] = {0, 32768, 49152, 65536, 98304};
  out[(size_t)l * 114688 + dofs[mat] + idx] = f2bf(src[k * 128 + n]);
}

// ---------------------------------------------------------------------------
__global__ void copy_kernel(const float* __restrict__ src, float* __restrict__ dst, int n) {
  int i = blockIdx.x * blockDim.x + threadIdx.x;
  if (i < n) dst[i] = src[i];
}

// ---------------------------------------------------------------------------
// h_init_mfma: 16 nodes/block (384 blocks), 512 threads.
// Rounds>=1: A=silu(Hmem); u=silu(A@mW1+mb1); h0=embed[S]+(u@mW2+mb2);
// Round 0:   h0=embed[S].
// Then H=h0@W_in+b_in -> Hout (fp32) ; PQ0 = H@[W1a|W1b] (bf16) for layer 0.
// ---------------------------------------------------------------------------
__global__ __launch_bounds__(512) void h_init_mfma(
    const float* __restrict__ embed, const int* __restrict__ S,
    const short* __restrict__ W_inT, const float* __restrict__ b_in,
    const float* __restrict__ Hmem,
    const short* __restrict__ mW1T, const float* __restrict__ mb1,
    const short* __restrict__ mW2T, const float* __restrict__ mb2,
    const short* __restrict__ W1T0,
    float* __restrict__ Hout, short* __restrict__ PQ0)
{
  __shared__ __align__(16) short A[16 * HD];
  __shared__ __align__(16) short Bu[16 * HD];
  __shared__ __align__(16) short h0B[16 * ED];
  __shared__ __align__(16) short HB[16 * HD];
  const int t = threadIdx.x;
  const int m0 = blockIdx.x * 16;
  const int wid = t >> 6, lane = t & 63, lr = lane & 15, lk = lane >> 4;

  if (Hmem) {
    {
      const int r = t >> 5, c4 = t & 31;
      const float4 v = ((const float4*)Hmem)[(size_t)(m0 + r) * 32 + c4];
      short4v s;
      s.x = f2bf(silu_f(v.x)); s.y = f2bf(silu_f(v.y));
      s.z = f2bf(silu_f(v.z)); s.w = f2bf(silu_f(v.w));
      *(short4v*)&A[swz128(r, c4 * 4)] = s;
    }
    __syncthreads();
    {  // u = silu(A @ mW1T + mb1) -> Bu
      f32x4 acc[2] = {};
#pragma unroll
      for (int ks = 0; ks < 4; ++ks) {
        const int k0 = ks * 32 + lk * 8;
        const short8 a = *(const short8*)&A[swz128(lr, k0)];
#pragma unroll
        for (int ni = 0; ni < 2; ++ni) {
          const int c = (wid * 2 + ni) * 16 + lr;
          acc[ni] = mfma16(a, *(const short8*)(mW1T + c * 128 + k0), acc[ni]);
        }
      }
#pragma unroll
      for (int ni = 0; ni < 2; ++ni) {
        const int col = (wid * 2 + ni) * 16 + lr;
        const float bias = mb1[col];
#pragma unroll
        for (int g = 0; g < 4; ++g)
          Bu[swz128(lk * 4 + g, col)] = f2bf(silu_f(acc[ni][g] + bias));
      }
    }
    __syncthreads();
    if (wid < 4) {  // h0 = embed[S] + u @ mW2T + mb2 (64 cols)
      f32x4 acc = {};
#pragma unroll
      for (int ks = 0; ks < 4; ++ks) {
        const int k0 = ks * 32 + lk * 8;
        const short8 a = *(const short8*)&Bu[swz128(lr, k0)];
        const int c = wid * 16 + lr;
        acc = mfma16(a, *(const short8*)(mW2T + c * 128 + k0), acc);
      }
      const int col = wid * 16 + lr;
      const float bias = mb2[col];
#pragma unroll
      for (int g = 0; g < 4; ++g) {
        const int row = lk * 4 + g;
        h0B[swz64(row, col)] = f2bf(embed[S[m0 + row] * ED + col] + acc[g] + bias);
      }
    }
  } else {
    for (int idx = t; idx < 16 * ED; idx += 512) {
      const int row = idx >> 6, col = idx & 63;
      h0B[swz64(row, col)] = f2bf(embed[S[m0 + row] * ED + col]);
    }
  }
  __syncthreads();
  {  // H = h0 @ W_inT + b_in -> Hout global fp32 + HB bf16
    f32x4 acc = {};
#pragma unroll
    for (int ks = 0; ks < 2; ++ks) {
      const int k0 = ks * 32 + lk * 8;
      const short8 a = *(const short8*)&h0B[swz64(lr, k0)];
      const int c = wid * 16 + lr;
      acc = mfma16(a, *(const short8*)(W_inT + c * 64 + k0), acc);
    }
    const int col = wid * 16 + lr;
    const float bias = b_in[col];
#pragma unroll
    for (int g = 0; g < 4; ++g) {
      const int row = lk * 4 + g;
      const float hv = acc[g] + bias;
      Hout[(size_t)(m0 + row) * HD + col] = hv;
      HB[swz128(row, col)] = f2bf(hv);
    }
  }
  __syncthreads();
  {  // PQ0 = HB @ [W1a|W1b]  (256 cols, 2 n-tiles/wave)
    f32x4 acc[2] = {};
#pragma unroll
    for (int ks = 0; ks < 4; ++ks) {
      const int k0 = ks * 32 + lk * 8;
      const short8 a = *(const short8*)&HB[swz128(lr, k0)];
#pragma unroll
      for (int ni = 0; ni < 2; ++ni) {
        const int c = (wid * 2 + ni) * 16 + lr;
        const short* bp = (c < HD) ? (W1T0 + c * 256 + k0)
                                   : (W1T0 + (c - HD) * 256 + HD + k0);
        acc[ni] = mfma16(a, *(const short8*)bp, acc[ni]);
      }
    }
#pragma unroll
    for (int ni = 0; ni < 2; ++ni) {
      const int c = (wid * 2 + ni) * 16 + lr;
#pragma unroll
      for (int g = 0; g < 4; ++g)
        PQ0[(size_t)(m0 + lk * 4 + g) * 256 + c] = f2bf(acc[ni][g]);
    }
  }
}

// ---------------------------------------------------------------------------
// kNN: one wave per node, 8 nodes/block, candidates in registers, no barriers.
// ---------------------------------------------------------------------------
__global__ __launch_bounds__(512) void knn_kernel(const float* __restrict__ X,
                                                  int* __restrict__ nbr)
{
  const int w = threadIdx.x >> 6, lane = threadIdx.x & 63;
  const int i = blockIdx.x * 8 + w;
  const int base = (i / SEG) * SEG;

  const float cx = X[i * XD + 3], cy = X[i * XD + 4], cz = X[i * XD + 5];
  float dv[8];
  int   di[8];
#pragma unroll
  for (int q = 0; q < 8; ++q) {
    const int j = base + lane + q * 64;
    float dx = __fsub_rn(cx, X[j * XD + 3]);
    float dy = __fsub_rn(cy, X[j * XD + 4]);
    float dz = __fsub_rn(cz, X[j * XD + 5]);
    float d2 = __fadd_rn(__fadd_rn(__fmul_rn(dx, dx), __fmul_rn(dy, dy)), __fmul_rn(dz, dz));
    if (j == i) d2 = 1e9f;
    dv[q] = d2; di[q] = j;
  }
  for (int it = 0; it < KN; ++it) {
    float bv = dv[0]; int bi = di[0];
#pragma unroll
    for (int q = 1; q < 8; ++q)
      if (dv[q] < bv || (dv[q] == bv && di[q] < bi)) { bv = dv[q]; bi = di[q]; }
#pragma unroll
    for (int m = 1; m < 64; m <<= 1) {
      float ov = __shfl_xor(bv, m, 64);
      int   oi = __shfl_xor(bi, m, 64);
      if (ov < bv || (ov == bv && oi < bi)) { bv = ov; bi = oi; }
    }
    if (lane == 0) nbr[i * KN + it] = bi;
    const int rel = bi - base;
    const int oq = rel >> 6;
#pragma unroll
    for (int q = 0; q < 8; ++q)
      if (q == oq && (rel & 63) == lane) dv[q] = 3e38f;
  }
}

// ---------------------------------------------------------------------------
// Fused per-layer edge kernel. PQ input is bf16; tail phase produces next
// layer's PQ (when W1Tn != null) from the freshly computed H (LDS, bufA reuse).
// ---------------------------------------------------------------------------
__global__ __launch_bounds__(512) void edge_layer_kernel(
    const float* __restrict__ Hin,  float* __restrict__ Hout,
    const float* __restrict__ Xin,  float* __restrict__ Xout,
    const int*   __restrict__ nbr,  const float* __restrict__ channel_w,
    const short* __restrict__ PQ,
    const float* __restrict__ eW1,  const float* __restrict__ eb1,
    const float* __restrict__ eb2,  const float* __restrict__ cb1,
    const float* __restrict__ cW2,  const float* __restrict__ cb2,
    const float* __restrict__ nb1,  const float* __restrict__ nb2,
    const short* __restrict__ W2T,  const short* __restrict__ C1T,
    const short* __restrict__ N1T,  const short* __restrict__ N2T,
    const short* __restrict__ W1Tn, short* __restrict__ PQn)
{
  __shared__ __align__(16) short bufA[ROWS * HD];    // h1; later Hout bf16
  __shared__ __align__(16) short bufB[ROWS * HD];    // msg
  __shared__ __align__(16) short nodeA[NPB * 256];   // [Hi | agg]
  __shared__ __align__(16) short uT[NPB * HD];       // node hidden
  __shared__ float scalePart[ROWS][4];
  __shared__ int   nbrS[ROWS];
  short* houtB = bufA;   // bufA dead after G2; reused for Hout bf16

  const int t  = threadIdx.x;
  const int n0 = blockIdx.x * NPB;
  const int nvalid = (NNODE - n0 < NPB) ? (NNODE - n0) : NPB;
  const int evalid = nvalid * KN;

  // ---- P01: nbr + radial (8 thr/row, shfl-reduced) + h1 + nodeA-Hi ----
  {
    const int row  = t >> 3;          // 0..63
    const int part = t & 7;           // 0..7
    const bool rvalid = row < evalid;
    const int nd = row / KN;
    const int jn = rvalid ? nbr[n0 * KN + row] : n0;
    if (part == 0) nbrS[row] = jn;

    float r = 0.f;
    if (rvalid) {
      const float* xi = Xin + (size_t)(n0 + nd) * XD;
      const float* xj = Xin + (size_t)jn * XD;
      {
        const int c = part;
        float dx = xi[c * 3 + 0] - xj[c * 3 + 0];
        float dy = xi[c * 3 + 1] - xj[c * 3 + 1];
        float dz = xi[c * 3 + 2] - xj[c * 3 + 2];
        r += channel_w[c] * (dx * dx + dy * dy + dz * dz);
      }
      if (part < 6) {
        const int c = part + 8;
        float dx = xi[c * 3 + 0] - xj[c * 3 + 0];
        float dy = xi[c * 3 + 1] - xj[c * 3 + 1];
        float dz = xi[c * 3 + 2] - xj[c * 3 + 2];
        r += channel_w[c] * (dx * dx + dy * dy + dz * dz);
      }
    }
    r += __shfl_xor(r, 1, 64);
    r += __shfl_xor(r, 2, 64);
    r += __shfl_xor(r, 4, 64);

    // nodeA Hi half (224 threads)
    if (t < NPB * (HD / 4)) {
      const int r2 = t >> 5, c4 = t & 31;
      float4 v = make_float4(0.f, 0.f, 0.f, 0.f);
      if (r2 < nvalid) v = ((const float4*)Hin)[(size_t)(n0 + r2) * 32 + c4];
      short4v s;
      s.x = f2bf(v.x); s.y = f2bf(v.y); s.z = f2bf(v.z); s.w = f2bf(v.w);
      *(short4v*)&nodeA[swz256(r2, c4 * 4)] = s;
    }

    // h1 = silu(P[i] + Q[j] + radial*w256 + eb1) -> bufA
    const int inode = n0 + ((nd < nvalid) ? nd : 0);
    const short4v* PQv = (const short4v*)PQ;
    const float4* w2564 = (const float4*)(eW1 + 256 * HD);
    const float4* eb14 = (const float4*)eb1;
#pragma unroll
    for (int ii = 0; ii < 4; ++ii) {
      const int c4 = part + ii * 8;
      const short4v ps = PQv[(size_t)inode * 64 + c4];
      const short4v qs = PQv[(size_t)jn * 64 + 32 + c4];
      const float4 w = w2564[c4];
      const float4 bb = eb14[c4];
      short4v s;
      s.x = f2bf(silu_f(bf2f(ps.x) + bf2f(qs.x) + r * w.x + bb.x));
      s.y = f2bf(silu_f(bf2f(ps.y) + bf2f(qs.y) + r * w.y + bb.y));
      s.z = f2bf(silu_f(bf2f(ps.z) + bf2f(qs.z) + r * w.z + bb.z));
      s.w = f2bf(silu_f(bf2f(ps.w) + bf2f(qs.w) + r * w.w + bb.w));
      *(short4v*)&bufA[swz128(row, c4 * 4)] = s;
    }
  }
  __syncthreads();

  const int wid  = t >> 6;       // 0..7
  const int lane = t & 63;
  const int m2 = wid >> 2;       // 0..1
  const int n2 = wid & 3;        // 0..3
  const int lr = lane & 15;
  const int lk = lane >> 4;
  const int rA0 = (m2 * 2) * 16 + lr;
  const int rA1 = rA0 + 16;

  // ---- G2: msg = silu(h1 @ eW2 + eb2) -> bufB ----
  {
    f32x4 acc[2][2] = {};
    const short* b0p = W2T + ((n2 * 2) * 16 + lr) * 128;
    const short* b1p = b0p + 16 * 128;
#pragma unroll
    for (int ks = 0; ks < 4; ++ks) {
      const int k0 = ks * 32 + lk * 8;
      const short8 a0 = *(const short8*)&bufA[swz128(rA0, k0)];
      const short8 a1 = *(const short8*)&bufA[swz128(rA1, k0)];
      const short8 b0 = *(const short8*)(b0p + k0);
      const short8 b1 = *(const short8*)(b1p + k0);
      acc[0][0] = mfma16(a0, b0, acc[0][0]);
      acc[0][1] = mfma16(a0, b1, acc[0][1]);
      acc[1][0] = mfma16(a1, b0, acc[1][0]);
      acc[1][1] = mfma16(a1, b1, acc[1][1]);
    }
#pragma unroll
    for (int ni = 0; ni < 2; ++ni) {
      const int col = (n2 * 2 + ni) * 16 + lr;
      const float bias = eb2[col];
#pragma unroll
      for (int mi = 0; mi < 2; ++mi) {
        const int rb = (m2 * 2 + mi) * 16 + lk * 4;
#pragma unroll
        for (int g = 0; g < 4; ++g)
          bufB[swz128(rb + g, col)] = f2bf(silu_f(acc[mi][ni][g] + bias));
      }
    }
  }
  __syncthreads();

  // ---- G3: scale partials in-register; agg -> nodeA cols 128.. ----
  {
    f32x4 acc[2][2] = {};
    const short* b0p = C1T + ((n2 * 2) * 16 + lr) * 128;
    const short* b1p = b0p + 16 * 128;
#pragma unroll
    for (int ks = 0; ks < 4; ++ks) {
      const int k0 = ks * 32 + lk * 8;
      const short8 a0 = *(const short8*)&bufB[swz128(rA0, k0)];
      const short8 a1 = *(const short8*)&bufB[swz128(rA1, k0)];
      const short8 b0 = *(const short8*)(b0p + k0);
      const short8 b1 = *(const short8*)(b1p + k0);
      acc[0][0] = mfma16(a0, b0, acc[0][0]);
      acc[0][1] = mfma16(a0, b1, acc[0][1]);
      acc[1][0] = mfma16(a1, b0, acc[1][0]);
      acc[1][1] = mfma16(a1, b1, acc[1][1]);
    }
    float p[2][4];
#pragma unroll
    for (int mi = 0; mi < 2; ++mi)
#pragma unroll
      for (int g = 0; g < 4; ++g) p[mi][g] = 0.f;
#pragma unroll
    for (int ni = 0; ni < 2; ++ni) {
      const int col = (n2 * 2 + ni) * 16 + lr;
      const float bias = cb1[col];
      const float wv = cW2[col];
#pragma unroll
      for (int mi = 0; mi < 2; ++mi)
#pragma unroll
        for (int g = 0; g < 4; ++g)
          p[mi][g] = fmaf(silu_f(acc[mi][ni][g] + bias), wv, p[mi][g]);
    }
#pragma unroll
    for (int m = 1; m < 16; m <<= 1) {
#pragma unroll
      for (int mi = 0; mi < 2; ++mi)
#pragma unroll
        for (int g = 0; g < 4; ++g)
          p[mi][g] += __shfl_xor(p[mi][g], m, 64);
    }
    if (lr == 0) {
#pragma unroll
      for (int mi = 0; mi < 2; ++mi)
#pragma unroll
        for (int g = 0; g < 4; ++g)
          scalePart[(m2 * 2 + mi) * 16 + lk * 4 + g][n2] = p[mi][g];
    }
  }
  for (int idx = t; idx < NPB * HD; idx += 512) {
    const int r2 = idx >> 7, col = idx & 127;
    float v = 0.f;
    if (r2 < nvalid) {
#pragma unroll
      for (int k = 0; k < KN; ++k) v += bf2f(bufB[swz128(r2 * KN + k, col)]);
    }
    nodeA[swz256(r2, col + HD)] = f2bf(v);
  }
  __syncthreads();

  // ---- P5: NG1 (u = silu([H|agg] @ nW1 + nb1)) ; X update ----
  {
    f32x4 acc = {};
    const short* bp = N1T + (wid * 16 + lr) * 256;
#pragma unroll
    for (int ks = 0; ks < 8; ++ks) {
      const int k0 = ks * 32 + lk * 8;
      short8 a = {0, 0, 0, 0, 0, 0, 0, 0};
      if (lr < NPB) a = *(const short8*)&nodeA[swz256(lr, k0)];
      const short8 b = *(const short8*)(bp + k0);
      acc = mfma16(a, b, acc);
    }
    const int col = wid * 16 + lr;
    const float bias = nb1[col];
#pragma unroll
    for (int g = 0; g < 4; ++g) {
      const int orow = lk * 4 + g;
      if (orow < NPB) uT[swz128(orow, col)] = f2bf(silu_f(acc[g] + bias));
    }
  }
  {
    const float c2 = cb2[0];
    for (int idx = t; idx < NPB * XD; idx += 512) {
      const int nd = idx / XD, e = idx - nd * XD;
      if (nd < nvalid) {
        const float xi = Xin[(size_t)n0 * XD + idx];
        float a = 0.f;
#pragma unroll
        for (int k = 0; k < KN; ++k) {
          const int r = nd * KN + k;
          const float sc = ((scalePart[r][0] + scalePart[r][1])
                          + (scalePart[r][2] + scalePart[r][3])) + c2;
          a += (xi - Xin[(size_t)nbrS[r] * XD + e]) * sc;
        }
        Xout[(size_t)(n0 + nd) * XD + e] = xi + a / 9.0f;
      }
    }
  }
  __syncthreads();

  // ---- NG2: Hout = Hi + u @ nW2 + nb2 (+ stash bf16 Hout in houtB) ----
  {
    f32x4 acc = {};
    const short* bp = N2T + (wid * 16 + lr) * 128;
#pragma unroll
    for (int ks = 0; ks < 4; ++ks) {
      const int k0 = ks * 32 + lk * 8;
      short8 a = {0, 0, 0, 0, 0, 0, 0, 0};
      if (lr < NPB) a = *(const short8*)&uT[swz128(lr, k0)];
      const short8 b = *(const short8*)(bp + k0);
      acc = mfma16(a, b, acc);
    }
    const int col = wid * 16 + lr;
    const float bias = nb2[col];
#pragma unroll
    for (int g = 0; g < 4; ++g) {
      const int row = lk * 4 + g;
      if (row < nvalid) {
        const float hv = Hin[(size_t)(n0 + row) * HD + col] + acc[g] + bias;
        Hout[(size_t)(n0 + row) * HD + col] = hv;
        if (W1Tn) houtB[swz128(row, col)] = f2bf(hv);
      }
    }
  }

  // ---- PQn: next layer's PQ = Hout @ [W1a|W1b] ----
  if (W1Tn) {
    __syncthreads();
    f32x4 acc[2] = {};
#pragma unroll
    for (int ks = 0; ks < 4; ++ks) {
      const int k0 = ks * 32 + lk * 8;
      short8 a = {0, 0, 0, 0, 0, 0, 0, 0};
      if (lr < NPB) a = *(const short8*)&houtB[swz128(lr, k0)];
#pragma unroll
      for (int ni = 0; ni < 2; ++ni) {
        const int c = (wid * 2 + ni) * 16 + lr;
        const short* bp = (c < HD) ? (W1Tn + c * 256 + k0)
                                   : (W1Tn + (c - HD) * 256 + HD + k0);
        acc[ni] = mfma16(a, *(const short8*)bp, acc[ni]);
      }
    }
#pragma unroll
    for (int ni = 0; ni < 2; ++ni) {
      const int c = (wid * 2 + ni) * 16 + lr;
#pragma unroll
      for (int g = 0; g < 4; ++g) {
        const int row = lk * 4 + g;
        if (row < nvalid) PQn[(size_t)(n0 + row) * 256 + c] = f2bf(acc[ni][g]);
      }
    }
  }
}

// ---------------------------------------------------------------------------
// Output head (4-way ILP unroll)
// ---------------------------------------------------------------------------
__global__ __launch_bounds__(128) void out_kernel(
    const float* __restrict__ H, const float* __restrict__ X,
    const float* __restrict__ oW1, const float* __restrict__ ob1,
    const float* __restrict__ oW2, const float* __restrict__ ob2,
    float* __restrict__ out)
{
  __shared__ float hs[HD];
  __shared__ float u[HD];
  const int i = blockIdx.x, j = threadIdx.x;

  hs[j] = silu_f(H[i * HD + j]);
  __syncthreads();
  float a0 = 0.f, a1 = 0.f, a2 = 0.f, a3 = 0.f;
  for (int k = 0; k < HD; k += 4) {
    a0 = fmaf(hs[k + 0], oW1[(k + 0) * HD + j], a0);
    a1 = fmaf(hs[k + 1], oW1[(k + 1) * HD + j], a1);
    a2 = fmaf(hs[k + 2], oW1[(k + 2) * HD + j], a2);
    a3 = fmaf(hs[k + 3], oW1[(k + 3) * HD + j], a3);
  }
  u[j] = silu_f(ob1[j] + ((a0 + a1) + (a2 + a3)));
  __syncthreads();
  if (j < NCLS) {
    float o0 = 0.f, o1 = 0.f, o2 = 0.f, o3 = 0.f;
    for (int k = 0; k < HD; k += 4) {
      o0 = fmaf(u[k + 0], oW2[(k + 0) * NCLS + j], o0);
      o1 = fmaf(u[k + 1], oW2[(k + 1) * NCLS + j], o1);
      o2 = fmaf(u[k + 2], oW2[(k + 2) * NCLS + j], o2);
      o3 = fmaf(u[k + 3], oW2[(k + 3) * NCLS + j], o3);
    }
    out[i * NCLS + j] = ob2[j] + ((o0 + o1) + (o2 + o3));
  }
  if (j < XD) out[NNODE * NCLS + i * XD + j] = X[i * XD + j];
}

// ---------------------------------------------------------------------------
extern "C" void kernel_launch(void* const* d_in, const int* in_sizes, int n_in,
                              void* d_out, int out_size, void* d_ws, size_t ws_size,
                              hipStream_t stream)
{
  const float* X0       = (const float*)d_in[0];
  const int*   S        = (const int*)  d_in[1];
  const float* embed    = (const float*)d_in[3];
  const float* W_in     = (const float*)d_in[4];
  const float* b_in     = (const float*)d_in[5];
  const float* channelw = (const float*)d_in[6];
  const float* eW1      = (const float*)d_in[7];
  const float* eb1      = (const float*)d_in[8];
  const float* eW2      = (const float*)d_in[9];
  const float* eb2      = (const float*)d_in[10];
  const float* cW1      = (const float*)d_in[11];
  const float* cb1      = (const float*)d_in[12];
  const float* cW2      = (const float*)d_in[13];
  const float* cb2      = (const float*)d_in[14];
  const float* nW1      = (const float*)d_in[15];
  const float* nb1      = (const float*)d_in[16];
  const float* nW2      = (const float*)d_in[17];
  const float* nb2      = (const float*)d_in[18];
  const float* mW1      = (const float*)d_in[19];
  const float* mb1      = (const float*)d_in[20];
  const float* mW2      = (const float*)d_in[21];
  const float* mb2      = (const float*)d_in[22];
  const float* oW1      = (const float*)d_in[23];
  const float* ob1      = (const float*)d_in[24];
  const float* oW2      = (const float*)d_in[25];
  const float* ob2      = (const float*)d_in[26];

  char* ws = (char*)d_ws;
  const size_t HBYTES = (size_t)NNODE * HD * sizeof(float);      // 3,145,728
  const size_t XBYTES = (size_t)NNODE * XD * sizeof(float);      // 1,032,192
  const size_t NBRB   = (size_t)NNODE * KN * sizeof(int);        // 221,184
  const size_t WBFB   = (size_t)WBF_SHORTS * sizeof(short);      // 753,664
  const size_t PQB    = (size_t)NNODE * 256 * sizeof(short);     // 3,145,728
  float* Hb[2] = { (float*)(ws), (float*)(ws + HBYTES) };
  float* Xb[2] = { (float*)(ws + 2 * HBYTES), (float*)(ws + 2 * HBYTES + XBYTES) };
  int*   nbr   = (int*)(ws + 2 * HBYTES + 2 * XBYTES);
  short* Wbf   = (short*)(ws + 2 * HBYTES + 2 * XBYTES + NBRB);
  short* PQb[2] = { (short*)(ws + 2 * HBYTES + 2 * XBYTES + NBRB + WBFB),
                    (short*)(ws + 2 * HBYTES + 2 * XBYTES + NBRB + WBFB + PQB) };

  prep_weights<<<dim3(128, 16), 256, 0, stream>>>(eW1, eW2, cW1, nW1, nW2,
                                                  mW1, mW2, W_in, Wbf);
  copy_kernel<<<(NNODE * XD + 255) / 256, 256, 0, stream>>>(X0, Xb[0], NNODE * XD);

  int hc = 0, xc = 0;
  for (int t = 0; t < 3; ++t) {
    const float* Hmem = (t == 0) ? nullptr : Hb[hc];
    h_init_mfma<<<NNODE / 16, 512, 0, stream>>>(
        embed, S, Wbf + EXOFF + 24576, b_in, Hmem,
        Wbf + EXOFF, mb1, Wbf + EXOFF + 16384, mb2,
        Wbf /* layer-0 eW1T */, Hb[hc ^ 1], PQb[0]);
    hc ^= 1;
    knn_kernel<<<NNODE / 8, 512, 0, stream>>>(Xb[xc], nbr);
    for (int l = 0; l < 3; ++l) {
      const short* Wl = Wbf + (size_t)l * 114688;
      const short* Wn = (l < 2) ? (Wbf + (size_t)(l + 1) * 114688) : nullptr;
      const short* pqr = (l == 1) ? PQb[1] : PQb[0];
      short* pqw = (l == 0) ? PQb[1] : ((l == 1) ? PQb[0] : nullptr);
      edge_layer_kernel<<<EDGE_BLOCKS, 512, 0, stream>>>(
          Hb[hc], Hb[hc ^ 1], Xb[xc], Xb[xc ^ 1], nbr, channelw, pqr,
          eW1 + (size_t)l * 257 * HD, eb1 + (size_t)l * HD,
          eb2 + (size_t)l * HD,  cb1 + (size_t)l * HD,
          cW2 + (size_t)l * HD,  cb2 + (size_t)l,
          nb1 + (size_t)l * HD,  nb2 + (size_t)l * HD,
          Wl + 32768, Wl + 49152, Wl + 65536, Wl + 98304,
          Wn, pqw);
      hc ^= 1; xc ^= 1;
    }
  }
  out_kernel<<<NNODE, HD, 0, stream>>>(Hb[hc], Xb[xc], oW1, ob1, oW2, ob2, (float*)d_out);
}